// Round 1
// baseline (271.799 us; speedup 1.0000x reference)
//
#include <hip/hip_runtime.h>
#include <stdint.h>

#define S_LEN 2048
#define DMODEL 2048
#define NH 32
#define NKV 8
#define HD 64

typedef __attribute__((ext_vector_type(8))) __bf16 bf16x8;
typedef __attribute__((ext_vector_type(4))) float f32x4;

__device__ __forceinline__ unsigned short f2bf(float f) {
    union { float f; uint32_t u; } v; v.f = f;
    uint32_t u = v.u;
    u += 0x7FFFu + ((u >> 16) & 1u);
    return (unsigned short)(u >> 16);
}

#define GLDS16(g, l)                                                          \
    __builtin_amdgcn_global_load_lds(                                         \
        (const __attribute__((address_space(1))) unsigned int*)(g),           \
        (__attribute__((address_space(3))) unsigned int*)(l), 16, 0, 0)

// ---------------- elementwise cast fp32 -> bf16 ----------------
__global__ void cast_bf16_kernel(const float* __restrict__ src,
                                 unsigned short* __restrict__ dst, int n) {
    int g = (blockIdx.x * blockDim.x + threadIdx.x) * 8;
    if (g >= n) return;
    float4 a = *(const float4*)&src[g];
    float4 b = *(const float4*)&src[g + 4];
    unsigned short o[8];
    o[0] = f2bf(a.x); o[1] = f2bf(a.y); o[2] = f2bf(a.z); o[3] = f2bf(a.w);
    o[4] = f2bf(b.x); o[5] = f2bf(b.y); o[6] = f2bf(b.z); o[7] = f2bf(b.w);
    *(uint4*)&dst[g] = *(const uint4*)o;
}

// ---------------- tiled transpose + cast: dst[c][r] = bf16(src[r][c]) ------
__global__ void transpose_cast_kernel(const float* __restrict__ src,
                                      unsigned short* __restrict__ dst,
                                      int R, int C) {
    __shared__ float tile[32][33];
    int c0 = blockIdx.x * 32, r0 = blockIdx.y * 32;
    int tx = threadIdx.x, ty = threadIdx.y;
#pragma unroll
    for (int i = 0; i < 32; i += 8)
        tile[ty + i][tx] = src[(size_t)(r0 + ty + i) * C + c0 + tx];
    __syncthreads();
#pragma unroll
    for (int i = 0; i < 32; i += 8)
        dst[(size_t)(c0 + ty + i) * R + r0 + tx] = f2bf(tile[tx][ty + i]);
}

// ---------------- m97-style bf16 GEMM: C[M][N] = A[M][K] * BT[N][K]^T ------
__global__ __launch_bounds__(256) void gemm_bt_kernel(
    const unsigned short* __restrict__ A, const unsigned short* __restrict__ BT,
    float* __restrict__ C, int M, int N, int K) {
    __shared__ unsigned short As[128 * 32];
    __shared__ unsigned short Bs[128 * 32];
    const int t = threadIdx.x;
    const int lane = t & 63, wave = t >> 6;
    const int wr = wave >> 1, wc = wave & 1;
    const int m0 = blockIdx.x * 128, n0 = blockIdx.y * 128;
    const int l15 = lane & 15, lhi = lane >> 4;
    f32x4 acc[4][4] = {};
    const unsigned short* ga = A + (size_t)(m0 + (t >> 2)) * K + (t & 3) * 8;
    const unsigned short* gb = BT + (size_t)(n0 + (t >> 2)) * K + (t & 3) * 8;
    unsigned short* la = As + t * 8;
    unsigned short* lb = Bs + t * 8;
    for (int k0 = 0; k0 < K; k0 += 32) {
        GLDS16(ga + k0, la);
        GLDS16(ga + (size_t)64 * K + k0, la + 64 * 32);
        GLDS16(gb + k0, lb);
        GLDS16(gb + (size_t)64 * K + k0, lb + 64 * 32);
        __syncthreads();
        bf16x8 af[4], bfr[4];
#pragma unroll
        for (int m = 0; m < 4; m++)
            af[m] = *(const bf16x8*)&As[(wr * 64 + m * 16 + l15) * 32 + lhi * 8];
#pragma unroll
        for (int n = 0; n < 4; n++)
            bfr[n] = *(const bf16x8*)&Bs[(wc * 64 + n * 16 + l15) * 32 + lhi * 8];
#pragma unroll
        for (int m = 0; m < 4; m++)
#pragma unroll
            for (int n = 0; n < 4; n++)
                acc[m][n] = __builtin_amdgcn_mfma_f32_16x16x32_bf16(
                    af[m], bfr[n], acc[m][n], 0, 0, 0);
        __syncthreads();
    }
#pragma unroll
    for (int m = 0; m < 4; m++) {
        int row = m0 + wr * 64 + m * 16 + lhi * 4;
#pragma unroll
        for (int n = 0; n < 4; n++) {
            int col = n0 + wc * 64 + n * 16 + l15;
#pragma unroll
            for (int r = 0; r < 4; r++)
                C[(size_t)(row + r) * N + col] = acc[m][n][r];
        }
    }
}

// ---------------- RoPE for Q: Cqkv fp32 -> Q bf16 [H][S][HD] ---------------
__global__ void rope_q_kernel(const float* __restrict__ Cqkv,
                              const float* __restrict__ cb,
                              const float* __restrict__ sb,
                              unsigned short* __restrict__ Q) {
    int g = blockIdx.x * 256 + threadIdx.x;  // 2048*32*32
    int i = g & 31;
    int h = (g >> 5) & 31;
    int s = g >> 10;
    float2 v = *(const float2*)&Cqkv[(size_t)s * 3072 + h * 64 + 2 * i];
    float cc = cb[s * 32 + i], ss = sb[s * 32 + i];
    ushort2 o;
    o.x = f2bf(v.x * cc - v.y * ss);
    o.y = f2bf(v.x * ss + v.y * cc);
    *(ushort2*)&Q[(size_t)h * (S_LEN * HD) + s * HD + 2 * i] = o;
}

// ---------------- RoPE for K: -> Kb bf16 [NKV][S][HD] ----------------------
__global__ void rope_k_kernel(const float* __restrict__ Cqkv,
                              const float* __restrict__ cb,
                              const float* __restrict__ sb,
                              unsigned short* __restrict__ Kb) {
    int g = blockIdx.x * 256 + threadIdx.x;  // 2048*8*32
    int i = g & 31;
    int kvh = (g >> 5) & 7;
    int s = g >> 8;
    float2 v = *(const float2*)&Cqkv[(size_t)s * 3072 + 2048 + kvh * 64 + 2 * i];
    float cc = cb[s * 32 + i], ss = sb[s * 32 + i];
    ushort2 o;
    o.x = f2bf(v.x * cc - v.y * ss);
    o.y = f2bf(v.x * ss + v.y * cc);
    *(ushort2*)&Kb[(size_t)kvh * (S_LEN * HD) + s * HD + 2 * i] = o;
}

// ---------------- V transpose: Cqkv fp32 -> VT bf16 [NKV][HD][S] -----------
__global__ void v_transpose_kernel(const float* __restrict__ Cqkv,
                                   unsigned short* __restrict__ VT) {
    __shared__ float tile[32][33];
    int kvh = blockIdx.z;
    int d0 = blockIdx.x * 32, s0 = blockIdx.y * 32;
    int tx = threadIdx.x, ty = threadIdx.y;
#pragma unroll
    for (int i = 0; i < 32; i += 8)
        tile[ty + i][tx] =
            Cqkv[(size_t)(s0 + ty + i) * 3072 + 2560 + kvh * 64 + d0 + tx];
    __syncthreads();
#pragma unroll
    for (int i = 0; i < 32; i += 8)
        VT[(size_t)kvh * (HD * S_LEN) + (size_t)(d0 + ty + i) * S_LEN + s0 + tx] =
            f2bf(tile[tx][ty + i]);
}

// ---------------- flash attention: Q[H][S][64] x K/V per kv-head -----------
__global__ __launch_bounds__(256) void flash_kernel(
    const unsigned short* __restrict__ Q, const unsigned short* __restrict__ Kg,
    const unsigned short* __restrict__ VTg, unsigned short* __restrict__ O) {
    __shared__ unsigned short Ks[64 * 64];
    __shared__ unsigned short Vs[64 * 64];
    __shared__ unsigned short Ps[4][16 * 64];
    const int t = threadIdx.x, lane = t & 63, wave = t >> 6;
    const int l15 = lane & 15, lhi = lane >> 4;
    const int h = blockIdx.y;
    const int q0 = (gridDim.x - 1 - blockIdx.x) * 64;  // long blocks first
    const int kvh = h >> 2;

    const unsigned short* qp =
        Q + ((size_t)h * S_LEN + q0 + wave * 16 + l15) * HD + lhi * 8;
    bf16x8 qf0 = *(const bf16x8*)qp;
    bf16x8 qf1 = *(const bf16x8*)(qp + 32);

    f32x4 oacc[4] = {};
    float mrun[4], lrun[4];
#pragma unroll
    for (int r = 0; r < 4; r++) { mrun[r] = -1e30f; lrun[r] = 0.f; }

    const int srow = t >> 3;
    const int scol = ((t & 7) * 8) ^ ((srow & 7) * 8);  // source-side swizzle
    const unsigned short* gk = Kg + ((size_t)kvh * S_LEN + srow) * HD + scol;
    const unsigned short* gv = VTg + ((size_t)kvh * HD + srow) * S_LEN + scol;
    unsigned short* lk = Ks + t * 8;
    unsigned short* lv = Vs + t * 8;

    const int nt = q0 / 64 + 1;
    const float cs = 0.125f * 1.44269504f;  // 1/sqrt(64) * log2(e)
    const int qrow = q0 + wave * 16 + lhi * 4;

    for (int kt = 0; kt < nt; kt++) {
        int kv0 = kt * 64;
        GLDS16(gk + (size_t)kv0 * HD, lk);
        GLDS16(gk + (size_t)(kv0 + 32) * HD, lk + 32 * 64);
        GLDS16(gv + kv0, lv);
        GLDS16(gv + (size_t)32 * S_LEN + kv0, lv + 32 * 64);
        __syncthreads();

        // S = Q K^T
        f32x4 sacc[4] = {};
#pragma unroll
        for (int nb = 0; nb < 4; nb++) {
            int krow = nb * 16 + l15;
            const unsigned short* kb = &Ks[krow * 64];
            int sw = (krow & 7) * 8;
            bf16x8 k0v = *(const bf16x8*)&kb[(lhi * 8) ^ sw];
            bf16x8 k1v = *(const bf16x8*)&kb[(32 + lhi * 8) ^ sw];
            sacc[nb] = __builtin_amdgcn_mfma_f32_16x16x32_bf16(qf0, k0v, sacc[nb], 0, 0, 0);
            sacc[nb] = __builtin_amdgcn_mfma_f32_16x16x32_bf16(qf1, k1v, sacc[nb], 0, 0, 0);
        }

        // online softmax (rows live on (lane>>4)*4+r, cols on lane&15)
        float p[4][4];
        float rmax[4] = {-1e30f, -1e30f, -1e30f, -1e30f};
#pragma unroll
        for (int nb = 0; nb < 4; nb++) {
            int kv = kv0 + nb * 16 + l15;
#pragma unroll
            for (int r = 0; r < 4; r++) {
                float sv = sacc[nb][r] * cs;
                sv = (kv <= qrow + r) ? sv : -1e30f;
                p[nb][r] = sv;
                rmax[r] = fmaxf(rmax[r], sv);
            }
        }
#pragma unroll
        for (int r = 0; r < 4; r++) {
            float v = rmax[r];
            v = fmaxf(v, __shfl_xor(v, 1));
            v = fmaxf(v, __shfl_xor(v, 2));
            v = fmaxf(v, __shfl_xor(v, 4));
            v = fmaxf(v, __shfl_xor(v, 8));
            float mnew = fmaxf(mrun[r], v);
            float sc = exp2f(mrun[r] - mnew);
            mrun[r] = mnew;
            lrun[r] *= sc;
            oacc[0][r] *= sc; oacc[1][r] *= sc;
            oacc[2][r] *= sc; oacc[3][r] *= sc;
        }
        unsigned short* pw = Ps[wave];
#pragma unroll
        for (int r = 0; r < 4; r++) {
            float ps = 0.f;
#pragma unroll
            for (int nb = 0; nb < 4; nb++) {
                float e = exp2f(p[nb][r] - mrun[r]);
                p[nb][r] = e;
                ps += e;
            }
            ps += __shfl_xor(ps, 1);
            ps += __shfl_xor(ps, 2);
            ps += __shfl_xor(ps, 4);
            ps += __shfl_xor(ps, 8);
            lrun[r] += ps;
            int qr = lhi * 4 + r;
#pragma unroll
            for (int nb = 0; nb < 4; nb++)
                pw[qr * 64 + ((nb * 16 + l15) ^ ((qr & 7) * 8))] = f2bf(p[nb][r]);
        }

        // O += P V
#pragma unroll
        for (int ks = 0; ks < 2; ks++) {
            int prow = l15;
            bf16x8 pf = *(const bf16x8*)&pw[prow * 64 + ((ks * 32 + lhi * 8) ^ ((prow & 7) * 8))];
#pragma unroll
            for (int db = 0; db < 4; db++) {
                int vrow = db * 16 + l15;
                bf16x8 vf = *(const bf16x8*)&Vs[vrow * 64 + ((ks * 32 + lhi * 8) ^ ((vrow & 7) * 8))];
                oacc[db] = __builtin_amdgcn_mfma_f32_16x16x32_bf16(pf, vf, oacc[db], 0, 0, 0);
            }
        }
        __syncthreads();
    }
#pragma unroll
    for (int db = 0; db < 4; db++)
#pragma unroll
        for (int r = 0; r < 4; r++) {
            float v = oacc[db][r] / lrun[r];
            O[((size_t)h * S_LEN + q0 + wave * 16 + lhi * 4 + r) * HD + db * 16 + l15] = f2bf(v);
        }
}

// ---------------- per-head fw GEMM + SiLU -> h2 bf16 [S][DMODEL] -----------
__global__ __launch_bounds__(256) void fw_silu_kernel(
    const unsigned short* __restrict__ AT, const unsigned short* __restrict__ fwT,
    const float* __restrict__ fb, unsigned short* __restrict__ h2) {
    const int t = threadIdx.x, lane = t & 63, wave = t >> 6;
    const int l15 = lane & 15, lhi = lane >> 4;
    const int r0 = blockIdx.x * 64 + wave * 16;
    const unsigned short* ap = AT + (size_t)(r0 + l15) * HD + lhi * 8;
    bf16x8 a0 = *(const bf16x8*)ap;
    bf16x8 a1 = *(const bf16x8*)(ap + 32);
    f32x4 acc[4] = {};
#pragma unroll
    for (int nb = 0; nb < 4; nb++) {
        const unsigned short* bp = fwT + (size_t)(nb * 16 + l15) * HD + lhi * 8;
        bf16x8 b0 = *(const bf16x8*)bp;
        bf16x8 b1 = *(const bf16x8*)(bp + 32);
        acc[nb] = __builtin_amdgcn_mfma_f32_16x16x32_bf16(a0, b0, acc[nb], 0, 0, 0);
        acc[nb] = __builtin_amdgcn_mfma_f32_16x16x32_bf16(a1, b1, acc[nb], 0, 0, 0);
    }
#pragma unroll
    for (int nb = 0; nb < 4; nb++) {
        int col = nb * 16 + l15;
        float bias = fb[col];
#pragma unroll
        for (int r = 0; r < 4; r++) {
            int row = r0 + lhi * 4 + r;  // h*S + s
            int s = row & (S_LEN - 1), hh = row >> 11;
            float x = acc[nb][r] + bias;
            float sg = 1.f / (1.f + exp2f(-x * 1.44269504f));
            h2[(size_t)s * DMODEL + hh * HD + col] = f2bf(x * sg);
        }
    }
}

extern "C" void kernel_launch(void* const* d_in, const int* in_sizes, int n_in,
                              void* d_out, int out_size, void* d_ws, size_t ws_size,
                              hipStream_t stream) {
    const float* x = (const float*)d_in[0];
    const float* fcos = (const float*)d_in[1];
    const float* fsin = (const float*)d_in[2];
    const float* wq = (const float*)d_in[4];
    const float* wk = (const float*)d_in[5];
    const float* wv = (const float*)d_in[6];
    const float* wo = (const float*)d_in[7];
    const float* fw = (const float*)d_in[8];
    const float* fb = (const float*)d_in[9];
    float* out = (float*)d_out;

    char* ws = (char*)d_ws;
    size_t off = 0;
    auto alloc = [&](size_t bytes) {
        void* p = ws + off;
        off += (bytes + 255) & ~(size_t)255;
        return p;
    };
    unsigned short* wqkvT = (unsigned short*)alloc((size_t)3072 * 2048 * 2);
    unsigned short* woT   = (unsigned short*)alloc((size_t)2048 * 2048 * 2);
    unsigned short* fwT   = (unsigned short*)alloc((size_t)64 * 64 * 2);
    float*          Cqkv  = (float*)alloc((size_t)2048 * 3072 * 4);
    unsigned short* Qb    = (unsigned short*)alloc((size_t)NH * S_LEN * HD * 2);
    unsigned short* Kb    = (unsigned short*)alloc((size_t)NKV * S_LEN * HD * 2);
    unsigned short* VT    = (unsigned short*)alloc((size_t)NKV * HD * S_LEN * 2);
    unsigned short* xb    = (unsigned short*)alloc((size_t)2048 * 2048 * 2);
    // aliases (lifetimes disjoint): attn reuses Cqkv space; h2 reuses xb space
    unsigned short* attn = (unsigned short*)Cqkv;
    unsigned short* h2 = xb;

    dim3 tb(32, 8);
    cast_bf16_kernel<<<2048, 256, 0, stream>>>(x, xb, 2048 * 2048);
    transpose_cast_kernel<<<dim3(64, 64), tb, 0, stream>>>(wq, wqkvT, 2048, 2048);
    transpose_cast_kernel<<<dim3(16, 64), tb, 0, stream>>>(wk, wqkvT + (size_t)2048 * 2048, 2048, 512);
    transpose_cast_kernel<<<dim3(16, 64), tb, 0, stream>>>(wv, wqkvT + (size_t)2560 * 2048, 2048, 512);
    transpose_cast_kernel<<<dim3(64, 64), tb, 0, stream>>>(wo, woT, 2048, 2048);
    transpose_cast_kernel<<<dim3(2, 2), tb, 0, stream>>>(fw, fwT, 64, 64);

    gemm_bt_kernel<<<dim3(16, 24), 256, 0, stream>>>(xb, wqkvT, Cqkv, 2048, 3072, 2048);

    rope_q_kernel<<<8192, 256, 0, stream>>>(Cqkv, fcos, fsin, Qb);
    rope_k_kernel<<<2048, 256, 0, stream>>>(Cqkv, fcos, fsin, Kb);
    v_transpose_kernel<<<dim3(2, 64, 8), tb, 0, stream>>>(Cqkv, VT);

    flash_kernel<<<dim3(32, 32), 256, 0, stream>>>(Qb, Kb, VT, attn);

    fw_silu_kernel<<<1024, 256, 0, stream>>>(attn, fwT, fb, h2);

    gemm_bt_kernel<<<dim3(16, 16), 256, 0, stream>>>(h2, woT, out, 2048, 2048, 2048);
}

// Round 2
// 233.716 us; speedup vs baseline: 1.1629x; 1.1629x over previous
//
#include <hip/hip_runtime.h>
#include <stdint.h>

#define S_LEN 2048
#define DMODEL 2048
#define NH 32
#define NKV 8
#define HD 64

typedef __attribute__((ext_vector_type(8))) __bf16 bf16x8;
typedef __attribute__((ext_vector_type(4))) float f32x4;

__device__ __forceinline__ unsigned short f2bf(float f) {
    union { float f; uint32_t u; } v; v.f = f;
    uint32_t u = v.u;
    u += 0x7FFFu + ((u >> 16) & 1u);
    return (unsigned short)(u >> 16);
}

#define GLDS16(g, l)                                                          \
    __builtin_amdgcn_global_load_lds(                                         \
        (const __attribute__((address_space(1))) unsigned int*)(g),           \
        (__attribute__((address_space(3))) unsigned int*)(l), 16, 0, 0)

// ---------------- elementwise cast fp32 -> bf16 ----------------
__global__ void cast_bf16_kernel(const float* __restrict__ src,
                                 unsigned short* __restrict__ dst, int n) {
    int g = (blockIdx.x * blockDim.x + threadIdx.x) * 8;
    if (g >= n) return;
    float4 a = *(const float4*)&src[g];
    float4 b = *(const float4*)&src[g + 4];
    unsigned short o[8];
    o[0] = f2bf(a.x); o[1] = f2bf(a.y); o[2] = f2bf(a.z); o[3] = f2bf(a.w);
    o[4] = f2bf(b.x); o[5] = f2bf(b.y); o[6] = f2bf(b.z); o[7] = f2bf(b.w);
    *(uint4*)&dst[g] = *(const uint4*)o;
}

// ---------------- tiled transpose + cast: dst[c][r] = bf16(src[r][c]) ------
__global__ void transpose_cast_kernel(const float* __restrict__ src,
                                      unsigned short* __restrict__ dst,
                                      int R, int C) {
    __shared__ float tile[32][33];
    int c0 = blockIdx.x * 32, r0 = blockIdx.y * 32;
    int tx = threadIdx.x, ty = threadIdx.y;
#pragma unroll
    for (int i = 0; i < 32; i += 8)
        tile[ty + i][tx] = src[(size_t)(r0 + ty + i) * C + c0 + tx];
    __syncthreads();
#pragma unroll
    for (int i = 0; i < 32; i += 8)
        dst[(size_t)(c0 + ty + i) * R + r0 + tx] = f2bf(tile[tx][ty + i]);
}

// ---------------- m97-style bf16 GEMM: C[M][N] = A[M][K] * BT[N][K]^T ------
__global__ __launch_bounds__(256) void gemm_bt_kernel(
    const unsigned short* __restrict__ A, const unsigned short* __restrict__ BT,
    float* __restrict__ C, int M, int N, int K) {
    __shared__ unsigned short As[128 * 32];
    __shared__ unsigned short Bs[128 * 32];
    const int t = threadIdx.x;
    const int lane = t & 63, wave = t >> 6;
    const int wr = wave >> 1, wc = wave & 1;
    const int m0 = blockIdx.x * 128, n0 = blockIdx.y * 128;
    const int l15 = lane & 15, lhi = lane >> 4;
    f32x4 acc[4][4] = {};
    const unsigned short* ga = A + (size_t)(m0 + (t >> 2)) * K + (t & 3) * 8;
    const unsigned short* gb = BT + (size_t)(n0 + (t >> 2)) * K + (t & 3) * 8;
    unsigned short* la = As + t * 8;
    unsigned short* lb = Bs + t * 8;
    for (int k0 = 0; k0 < K; k0 += 32) {
        GLDS16(ga + k0, la);
        GLDS16(ga + (size_t)64 * K + k0, la + 64 * 32);
        GLDS16(gb + k0, lb);
        GLDS16(gb + (size_t)64 * K + k0, lb + 64 * 32);
        __syncthreads();
        bf16x8 af[4], bfr[4];
#pragma unroll
        for (int m = 0; m < 4; m++)
            af[m] = *(const bf16x8*)&As[(wr * 64 + m * 16 + l15) * 32 + lhi * 8];
#pragma unroll
        for (int n = 0; n < 4; n++)
            bfr[n] = *(const bf16x8*)&Bs[(wc * 64 + n * 16 + l15) * 32 + lhi * 8];
#pragma unroll
        for (int m = 0; m < 4; m++)
#pragma unroll
            for (int n = 0; n < 4; n++)
                acc[m][n] = __builtin_amdgcn_mfma_f32_16x16x32_bf16(
                    af[m], bfr[n], acc[m][n], 0, 0, 0);
        __syncthreads();
    }
#pragma unroll
    for (int m = 0; m < 4; m++) {
        int row = m0 + wr * 64 + m * 16 + lhi * 4;
#pragma unroll
        for (int n = 0; n < 4; n++) {
            int col = n0 + wc * 64 + n * 16 + l15;
#pragma unroll
            for (int r = 0; r < 4; r++)
                C[(size_t)(row + r) * N + col] = acc[m][n][r];
        }
    }
}

// ---------------- RoPE for Q: Cqkv fp32 -> Q bf16 [H][S][HD] ---------------
__global__ void rope_q_kernel(const float* __restrict__ Cqkv,
                              const float* __restrict__ cb,
                              const float* __restrict__ sb,
                              unsigned short* __restrict__ Q) {
    int g = blockIdx.x * 256 + threadIdx.x;  // 2048*32*32
    int i = g & 31;
    int h = (g >> 5) & 31;
    int s = g >> 10;
    float2 v = *(const float2*)&Cqkv[(size_t)s * 3072 + h * 64 + 2 * i];
    float cc = cb[s * 32 + i], ss = sb[s * 32 + i];
    ushort2 o;
    o.x = f2bf(v.x * cc - v.y * ss);
    o.y = f2bf(v.x * ss + v.y * cc);
    *(ushort2*)&Q[(size_t)h * (S_LEN * HD) + s * HD + 2 * i] = o;
}

// ---------------- RoPE for K: -> Kb bf16 [NKV][S][HD] ----------------------
__global__ void rope_k_kernel(const float* __restrict__ Cqkv,
                              const float* __restrict__ cb,
                              const float* __restrict__ sb,
                              unsigned short* __restrict__ Kb) {
    int g = blockIdx.x * 256 + threadIdx.x;  // 2048*8*32
    int i = g & 31;
    int kvh = (g >> 5) & 7;
    int s = g >> 8;
    float2 v = *(const float2*)&Cqkv[(size_t)s * 3072 + 2048 + kvh * 64 + 2 * i];
    float cc = cb[s * 32 + i], ss = sb[s * 32 + i];
    ushort2 o;
    o.x = f2bf(v.x * cc - v.y * ss);
    o.y = f2bf(v.x * ss + v.y * cc);
    *(ushort2*)&Kb[(size_t)kvh * (S_LEN * HD) + s * HD + 2 * i] = o;
}

// ---------------- V transpose: Cqkv fp32 -> VT bf16 [NKV][HD][S] -----------
__global__ void v_transpose_kernel(const float* __restrict__ Cqkv,
                                   unsigned short* __restrict__ VT) {
    __shared__ float tile[32][33];
    int kvh = blockIdx.z;
    int d0 = blockIdx.x * 32, s0 = blockIdx.y * 32;
    int tx = threadIdx.x, ty = threadIdx.y;
#pragma unroll
    for (int i = 0; i < 32; i += 8)
        tile[ty + i][tx] =
            Cqkv[(size_t)(s0 + ty + i) * 3072 + 2560 + kvh * 64 + d0 + tx];
    __syncthreads();
#pragma unroll
    for (int i = 0; i < 32; i += 8)
        VT[(size_t)kvh * (HD * S_LEN) + (size_t)(d0 + ty + i) * S_LEN + s0 + tx] =
            f2bf(tile[tx][ty + i]);
}

// ---------------- flash attention v2 -----------------------------------
// 256 blocks (1/CU), 8 waves. Block b: head h=b&31, g=b>>5; processes two
// 128-row q-strips qt=15-g and qt=g -> 34 kv-tiles per block (balanced).
// K/V double-buffered in LDS, prefetch issued before compute, one barrier
// per tile (its vmcnt(0) drain lands after a full compute phase).
__global__ __launch_bounds__(512) void flash_kernel(
    const unsigned short* __restrict__ Q, const unsigned short* __restrict__ Kg,
    const unsigned short* __restrict__ VTg, unsigned short* __restrict__ O) {
    __shared__ unsigned short Ks[2][4096];
    __shared__ unsigned short Vs[2][4096];
    __shared__ unsigned short Ps[8][1024];
    const int t = threadIdx.x, lane = t & 63, wave = t >> 6;
    const int l15 = lane & 15, lhi = lane >> 4;
    const int b = blockIdx.x;
    const int h = b & 31, g = b >> 5;
    const int kvh = h >> 2;
    const float cs = 0.125f * 1.44269504f;  // 1/sqrt(64) * log2(e)

    // staging addresses: thread t covers row (t>>3), 8 elems at swizzled col
    const int srow = t >> 3;
    const int scol = ((t & 7) * 8) ^ ((srow & 7) * 8);  // source-side swizzle
    const unsigned short* gk = Kg + ((size_t)kvh * S_LEN + srow) * HD + scol;
    const unsigned short* gv = VTg + ((size_t)kvh * HD + srow) * S_LEN + scol;

#pragma unroll 1
    for (int item = 0; item < 2; ++item) {
        const int qt = (item == 0) ? (15 - g) : g;
        const int q0 = qt * 128;
        const int nt = 2 * qt + 2;
        const int wq = q0 + wave * 16;     // wave's first q row
        const int wqmax = wq + 15;         // wave's last q row
        const int qrow = wq + lhi * 4;     // this lane-group's first row

        const unsigned short* qp = Q + ((size_t)h * S_LEN + wq + l15) * HD + lhi * 8;
        bf16x8 qf0 = *(const bf16x8*)qp;
        bf16x8 qf1 = *(const bf16x8*)(qp + 32);

        f32x4 oacc[4] = {};
        float mrun[4], lrun[4];
#pragma unroll
        for (int r = 0; r < 4; r++) { mrun[r] = -1e30f; lrun[r] = 0.f; }

        // prologue: stage tile 0 into buf 0
        GLDS16(gk, &Ks[0][t * 8]);
        GLDS16(gv, &Vs[0][t * 8]);
        __syncthreads();

        int cur = 0;
#pragma unroll 1
        for (int kt = 0; kt < nt; ++kt) {
            const int kv0 = kt * 64;
            if (kt + 1 < nt) {  // prefetch next tile into other buffer
                GLDS16(gk + (size_t)(kv0 + 64) * HD, &Ks[cur ^ 1][t * 8]);
                GLDS16(gv + (kv0 + 64), &Vs[cur ^ 1][t * 8]);
            }
            if (kv0 <= wqmax) {  // wave-uniform causal skip
                // S = Q K^T
                f32x4 sacc[4] = {};
#pragma unroll
                for (int nb = 0; nb < 4; nb++) {
                    int krow = nb * 16 + l15;
                    const unsigned short* kb = &Ks[cur][krow * 64];
                    int sw = (krow & 7) * 8;
                    bf16x8 k0v = *(const bf16x8*)&kb[(lhi * 8) ^ sw];
                    bf16x8 k1v = *(const bf16x8*)&kb[(32 + lhi * 8) ^ sw];
                    sacc[nb] = __builtin_amdgcn_mfma_f32_16x16x32_bf16(qf0, k0v, sacc[nb], 0, 0, 0);
                    sacc[nb] = __builtin_amdgcn_mfma_f32_16x16x32_bf16(qf1, k1v, sacc[nb], 0, 0, 0);
                }
                // online softmax (rows on (lane>>4)*4+r, cols on lane&15)
                float p[4][4];
                float rmax[4] = {-1e30f, -1e30f, -1e30f, -1e30f};
#pragma unroll
                for (int nb = 0; nb < 4; nb++) {
                    int kv = kv0 + nb * 16 + l15;
#pragma unroll
                    for (int r = 0; r < 4; r++) {
                        float sv = sacc[nb][r] * cs;
                        sv = (kv <= qrow + r) ? sv : -1e30f;
                        p[nb][r] = sv;
                        rmax[r] = fmaxf(rmax[r], sv);
                    }
                }
#pragma unroll
                for (int r = 0; r < 4; r++) {
                    float v = rmax[r];
                    v = fmaxf(v, __shfl_xor(v, 1));
                    v = fmaxf(v, __shfl_xor(v, 2));
                    v = fmaxf(v, __shfl_xor(v, 4));
                    v = fmaxf(v, __shfl_xor(v, 8));
                    float mnew = fmaxf(mrun[r], v);
                    float sc = exp2f(mrun[r] - mnew);
                    mrun[r] = mnew;
                    lrun[r] *= sc;
                    oacc[0][r] *= sc; oacc[1][r] *= sc;
                    oacc[2][r] *= sc; oacc[3][r] *= sc;
                }
                unsigned short* pw = Ps[wave];
#pragma unroll
                for (int r = 0; r < 4; r++) {
                    float ps = 0.f;
#pragma unroll
                    for (int nb = 0; nb < 4; nb++) {
                        float e = exp2f(p[nb][r] - mrun[r]);
                        p[nb][r] = e;
                        ps += e;
                    }
                    ps += __shfl_xor(ps, 1);
                    ps += __shfl_xor(ps, 2);
                    ps += __shfl_xor(ps, 4);
                    ps += __shfl_xor(ps, 8);
                    lrun[r] += ps;
                    int qr = lhi * 4 + r;
#pragma unroll
                    for (int nb = 0; nb < 4; nb++)
                        pw[qr * 64 + ((nb * 16 + l15) ^ ((qr & 7) * 8))] = f2bf(p[nb][r]);
                }
                // O += P V
#pragma unroll
                for (int ks = 0; ks < 2; ks++) {
                    int prow = l15;
                    bf16x8 pf = *(const bf16x8*)&pw[prow * 64 + ((ks * 32 + lhi * 8) ^ ((prow & 7) * 8))];
#pragma unroll
                    for (int db = 0; db < 4; db++) {
                        int vrow = db * 16 + l15;
                        bf16x8 vf = *(const bf16x8*)&Vs[cur][vrow * 64 + ((ks * 32 + lhi * 8) ^ ((vrow & 7) * 8))];
                        oacc[db] = __builtin_amdgcn_mfma_f32_16x16x32_bf16(pf, vf, oacc[db], 0, 0, 0);
                    }
                }
            }
            __syncthreads();
            cur ^= 1;
        }
#pragma unroll
        for (int db = 0; db < 4; db++)
#pragma unroll
            for (int r = 0; r < 4; r++) {
                float v = oacc[db][r] / lrun[r];
                O[((size_t)h * S_LEN + wq + lhi * 4 + r) * HD + db * 16 + l15] = f2bf(v);
            }
    }
}

// ---------------- per-head fw GEMM + SiLU -> h2 bf16 [S][DMODEL] -----------
__global__ __launch_bounds__(256) void fw_silu_kernel(
    const unsigned short* __restrict__ AT, const unsigned short* __restrict__ fwT,
    const float* __restrict__ fb, unsigned short* __restrict__ h2) {
    const int t = threadIdx.x, lane = t & 63, wave = t >> 6;
    const int l15 = lane & 15, lhi = lane >> 4;
    const int r0 = blockIdx.x * 64 + wave * 16;
    const unsigned short* ap = AT + (size_t)(r0 + l15) * HD + lhi * 8;
    bf16x8 a0 = *(const bf16x8*)ap;
    bf16x8 a1 = *(const bf16x8*)(ap + 32);
    f32x4 acc[4] = {};
#pragma unroll
    for (int nb = 0; nb < 4; nb++) {
        const unsigned short* bp = fwT + (size_t)(nb * 16 + l15) * HD + lhi * 8;
        bf16x8 b0 = *(const bf16x8*)bp;
        bf16x8 b1 = *(const bf16x8*)(bp + 32);
        acc[nb] = __builtin_amdgcn_mfma_f32_16x16x32_bf16(a0, b0, acc[nb], 0, 0, 0);
        acc[nb] = __builtin_amdgcn_mfma_f32_16x16x32_bf16(a1, b1, acc[nb], 0, 0, 0);
    }
#pragma unroll
    for (int nb = 0; nb < 4; nb++) {
        int col = nb * 16 + l15;
        float bias = fb[col];
#pragma unroll
        for (int r = 0; r < 4; r++) {
            int row = r0 + lhi * 4 + r;  // h*S + s
            int s = row & (S_LEN - 1), hh = row >> 11;
            float x = acc[nb][r] + bias;
            float sg = 1.f / (1.f + exp2f(-x * 1.44269504f));
            h2[(size_t)s * DMODEL + hh * HD + col] = f2bf(x * sg);
        }
    }
}

extern "C" void kernel_launch(void* const* d_in, const int* in_sizes, int n_in,
                              void* d_out, int out_size, void* d_ws, size_t ws_size,
                              hipStream_t stream) {
    const float* x = (const float*)d_in[0];
    const float* fcos = (const float*)d_in[1];
    const float* fsin = (const float*)d_in[2];
    const float* wq = (const float*)d_in[4];
    const float* wk = (const float*)d_in[5];
    const float* wv = (const float*)d_in[6];
    const float* wo = (const float*)d_in[7];
    const float* fw = (const float*)d_in[8];
    const float* fb = (const float*)d_in[9];
    float* out = (float*)d_out;

    char* ws = (char*)d_ws;
    size_t off = 0;
    auto alloc = [&](size_t bytes) {
        void* p = ws + off;
        off += (bytes + 255) & ~(size_t)255;
        return p;
    };
    unsigned short* wqkvT = (unsigned short*)alloc((size_t)3072 * 2048 * 2);
    unsigned short* woT   = (unsigned short*)alloc((size_t)2048 * 2048 * 2);
    unsigned short* fwT   = (unsigned short*)alloc((size_t)64 * 64 * 2);
    float*          Cqkv  = (float*)alloc((size_t)2048 * 3072 * 4);
    unsigned short* Qb    = (unsigned short*)alloc((size_t)NH * S_LEN * HD * 2);
    unsigned short* Kb    = (unsigned short*)alloc((size_t)NKV * S_LEN * HD * 2);
    unsigned short* VT    = (unsigned short*)alloc((size_t)NKV * HD * S_LEN * 2);
    unsigned short* xb    = (unsigned short*)alloc((size_t)2048 * 2048 * 2);
    // aliases (lifetimes disjoint): attn reuses Cqkv space; h2 reuses xb space
    unsigned short* attn = (unsigned short*)Cqkv;
    unsigned short* h2 = xb;

    dim3 tb(32, 8);
    cast_bf16_kernel<<<2048, 256, 0, stream>>>(x, xb, 2048 * 2048);
    transpose_cast_kernel<<<dim3(64, 64), tb, 0, stream>>>(wq, wqkvT, 2048, 2048);
    transpose_cast_kernel<<<dim3(16, 64), tb, 0, stream>>>(wk, wqkvT + (size_t)2048 * 2048, 2048, 512);
    transpose_cast_kernel<<<dim3(16, 64), tb, 0, stream>>>(wv, wqkvT + (size_t)2560 * 2048, 2048, 512);
    transpose_cast_kernel<<<dim3(64, 64), tb, 0, stream>>>(wo, woT, 2048, 2048);
    transpose_cast_kernel<<<dim3(2, 2), tb, 0, stream>>>(fw, fwT, 64, 64);

    gemm_bt_kernel<<<dim3(16, 24), 256, 0, stream>>>(xb, wqkvT, Cqkv, 2048, 3072, 2048);

    rope_q_kernel<<<8192, 256, 0, stream>>>(Cqkv, fcos, fsin, Qb);
    rope_k_kernel<<<2048, 256, 0, stream>>>(Cqkv, fcos, fsin, Kb);
    v_transpose_kernel<<<dim3(2, 64, 8), tb, 0, stream>>>(Cqkv, VT);

    flash_kernel<<<256, 512, 0, stream>>>(Qb, Kb, VT, attn);

    fw_silu_kernel<<<1024, 256, 0, stream>>>(attn, fwT, fb, h2);

    gemm_bt_kernel<<<dim3(16, 16), 256, 0, stream>>>(h2, woT, out, 2048, 2048, 2048);
}

// Round 4
// 206.344 us; speedup vs baseline: 1.3172x; 1.1327x over previous
//
#include <hip/hip_runtime.h>
#include <stdint.h>

#define S_LEN 2048
#define DMODEL 2048
#define NH 32
#define NKV 8
#define HD 64

typedef __attribute__((ext_vector_type(8))) __bf16 bf16x8;
typedef __attribute__((ext_vector_type(4))) float f32x4;

__device__ __forceinline__ unsigned short f2bf(float f) {
    union { float f; uint32_t u; } v; v.f = f;
    uint32_t u = v.u;
    u += 0x7FFFu + ((u >> 16) & 1u);
    return (unsigned short)(u >> 16);
}

__device__ __forceinline__ uint32_t cvt_pk_bf16(float lo, float hi) {
    uint32_t r;
    asm("v_cvt_pk_bf16_f32 %0, %1, %2" : "=v"(r) : "v"(lo), "v"(hi));
    return r;
}

#define GLDS16(g, l)                                                          \
    __builtin_amdgcn_global_load_lds(                                         \
        (const __attribute__((address_space(1))) unsigned int*)(g),           \
        (__attribute__((address_space(3))) unsigned int*)(l), 16, 0, 0)

// ---------------- elementwise cast fp32 -> bf16 ----------------
__global__ void cast_bf16_kernel(const float* __restrict__ src,
                                 unsigned short* __restrict__ dst, int n) {
    int g = (blockIdx.x * blockDim.x + threadIdx.x) * 8;
    if (g >= n) return;
    float4 a = *(const float4*)&src[g];
    float4 b = *(const float4*)&src[g + 4];
    unsigned short o[8];
    o[0] = f2bf(a.x); o[1] = f2bf(a.y); o[2] = f2bf(a.z); o[3] = f2bf(a.w);
    o[4] = f2bf(b.x); o[5] = f2bf(b.y); o[6] = f2bf(b.z); o[7] = f2bf(b.w);
    *(uint4*)&dst[g] = *(const uint4*)o;
}

// ---------------- tiled transpose + cast: dst[c][r] = bf16(src[r][c]) ------
__global__ void transpose_cast_kernel(const float* __restrict__ src,
                                      unsigned short* __restrict__ dst,
                                      int R, int C) {
    __shared__ float tile[32][33];
    int c0 = blockIdx.x * 32, r0 = blockIdx.y * 32;
    int tx = threadIdx.x, ty = threadIdx.y;
#pragma unroll
    for (int i = 0; i < 32; i += 8)
        tile[ty + i][tx] = src[(size_t)(r0 + ty + i) * C + c0 + tx];
    __syncthreads();
#pragma unroll
    for (int i = 0; i < 32; i += 8)
        dst[(size_t)(c0 + ty + i) * R + r0 + tx] = f2bf(tile[tx][ty + i]);
}

// ------- 2-phase double-buffered bf16 GEMM: C[M][N] = A[M][K] * BT[N][K]^T --
__global__ __launch_bounds__(256) void gemm_bt_kernel(
    const unsigned short* __restrict__ A, const unsigned short* __restrict__ BT,
    float* __restrict__ C, int M, int N, int K) {
    __shared__ unsigned short As[2][128 * 32];
    __shared__ unsigned short Bs[2][128 * 32];
    const int t = threadIdx.x;
    const int lane = t & 63, wave = t >> 6;
    const int wr = wave >> 1, wc = wave & 1;
    const int m0 = blockIdx.x * 128, n0 = blockIdx.y * 128;
    const int l15 = lane & 15, lhi = lane >> 4;
    f32x4 acc[4][4] = {};
    const unsigned short* ga = A + (size_t)(m0 + (t >> 2)) * K + (t & 3) * 8;
    const unsigned short* gb = BT + (size_t)(n0 + (t >> 2)) * K + (t & 3) * 8;

    // prologue: stage K-tile 0 into buffer 0
    GLDS16(ga, &As[0][t * 8]);
    GLDS16(ga + (size_t)64 * K, &As[0][t * 8 + 64 * 32]);
    GLDS16(gb, &Bs[0][t * 8]);
    GLDS16(gb + (size_t)64 * K, &Bs[0][t * 8 + 64 * 32]);
    __syncthreads();

    int cur = 0;
    for (int k0 = 0; k0 < K; k0 += 32) {
        if (k0 + 32 < K) {  // prefetch next K-tile into other buffer
            GLDS16(ga + k0 + 32, &As[cur ^ 1][t * 8]);
            GLDS16(ga + (size_t)64 * K + k0 + 32, &As[cur ^ 1][t * 8 + 64 * 32]);
            GLDS16(gb + k0 + 32, &Bs[cur ^ 1][t * 8]);
            GLDS16(gb + (size_t)64 * K + k0 + 32, &Bs[cur ^ 1][t * 8 + 64 * 32]);
        }
        bf16x8 af[4], bfr[4];
#pragma unroll
        for (int m = 0; m < 4; m++)
            af[m] = *(const bf16x8*)&As[cur][(wr * 64 + m * 16 + l15) * 32 + lhi * 8];
#pragma unroll
        for (int n = 0; n < 4; n++)
            bfr[n] = *(const bf16x8*)&Bs[cur][(wc * 64 + n * 16 + l15) * 32 + lhi * 8];
#pragma unroll
        for (int m = 0; m < 4; m++)
#pragma unroll
            for (int n = 0; n < 4; n++)
                acc[m][n] = __builtin_amdgcn_mfma_f32_16x16x32_bf16(
                    af[m], bfr[n], acc[m][n], 0, 0, 0);
        __syncthreads();
        cur ^= 1;
    }
#pragma unroll
    for (int m = 0; m < 4; m++) {
        int row = m0 + wr * 64 + m * 16 + lhi * 4;
#pragma unroll
        for (int n = 0; n < 4; n++) {
            int col = n0 + wc * 64 + n * 16 + l15;
#pragma unroll
            for (int r = 0; r < 4; r++)
                C[(size_t)(row + r) * N + col] = acc[m][n][r];
        }
    }
}

// ---------------- RoPE for Q: Cqkv fp32 -> Q bf16 [H][S][HD] ---------------
__global__ void rope_q_kernel(const float* __restrict__ Cqkv,
                              const float* __restrict__ cb,
                              const float* __restrict__ sb,
                              unsigned short* __restrict__ Q) {
    int g = blockIdx.x * 256 + threadIdx.x;  // 2048*32*32
    int i = g & 31;
    int h = (g >> 5) & 31;
    int s = g >> 10;
    float2 v = *(const float2*)&Cqkv[(size_t)s * 3072 + h * 64 + 2 * i];
    float cc = cb[s * 32 + i], ss = sb[s * 32 + i];
    ushort2 o;
    o.x = f2bf(v.x * cc - v.y * ss);
    o.y = f2bf(v.x * ss + v.y * cc);
    *(ushort2*)&Q[(size_t)h * (S_LEN * HD) + s * HD + 2 * i] = o;
}

// ---------------- RoPE for K: -> Kb bf16 [NKV][S][HD] ----------------------
__global__ void rope_k_kernel(const float* __restrict__ Cqkv,
                              const float* __restrict__ cb,
                              const float* __restrict__ sb,
                              unsigned short* __restrict__ Kb) {
    int g = blockIdx.x * 256 + threadIdx.x;  // 2048*8*32
    int i = g & 31;
    int kvh = (g >> 5) & 7;
    int s = g >> 8;
    float2 v = *(const float2*)&Cqkv[(size_t)s * 3072 + 2048 + kvh * 64 + 2 * i];
    float cc = cb[s * 32 + i], ss = sb[s * 32 + i];
    ushort2 o;
    o.x = f2bf(v.x * cc - v.y * ss);
    o.y = f2bf(v.x * ss + v.y * cc);
    *(ushort2*)&Kb[(size_t)kvh * (S_LEN * HD) + s * HD + 2 * i] = o;
}

// ---------------- V transpose: Cqkv fp32 -> VT bf16 [NKV][HD][S] -----------
__global__ void v_transpose_kernel(const float* __restrict__ Cqkv,
                                   unsigned short* __restrict__ VT) {
    __shared__ float tile[32][33];
    int kvh = blockIdx.z;
    int d0 = blockIdx.x * 32, s0 = blockIdx.y * 32;
    int tx = threadIdx.x, ty = threadIdx.y;
#pragma unroll
    for (int i = 0; i < 32; i += 8)
        tile[ty + i][tx] =
            Cqkv[(size_t)(s0 + ty + i) * 3072 + 2560 + kvh * 64 + d0 + tx];
    __syncthreads();
#pragma unroll
    for (int i = 0; i < 32; i += 8)
        VT[(size_t)kvh * (HD * S_LEN) + (size_t)(d0 + ty + i) * S_LEN + s0 + tx] =
            f2bf(tile[tx][ty + i]);
}

// ---------------- flash attention v3: swapped QK^T, in-register softmax ----
// 256 blocks, 8 waves. Block b: head h=b&31, g=b>>5; strips qt=15-g and qt=g.
// S^T = mfma(K,Q): lane owns ONE q (col=lane&15), 16 kv values in regs.
// Softmax: 2 shfl per reduce. P routed to PV B-operand in-register.
// Routing (derived, lane lhi after xor32: A=P(lhi,pair(lhi>>1)),
// B=P(lhi^2,pair(lhi>>1)); after xor16 receives R):
//   lhi: 0 -> F01=A, F23=R | 1 -> F01=R, F23=B | 2 -> F01=B, F23=R | 3 -> F01=R, F23=A
__global__ __launch_bounds__(512) void flash_kernel(
    const unsigned short* __restrict__ Q, const unsigned short* __restrict__ Kg,
    const unsigned short* __restrict__ VTg, unsigned short* __restrict__ O) {
    __shared__ unsigned short Ks[2][4096];
    __shared__ unsigned short Vs[2][4096];
    const int t = threadIdx.x, lane = t & 63, wave = t >> 6;
    const int l15 = lane & 15, lhi = lane >> 4;
    const int b = blockIdx.x;
    const int h = b & 31, g = b >> 5;
    const int kvh = h >> 2;
    const float cs = 0.125f * 1.44269504f;  // 1/sqrt(64) * log2(e)

    const int srow = t >> 3;
    const int scol = ((t & 7) * 8) ^ ((srow & 7) * 8);  // source-side swizzle
    const unsigned short* gk = Kg + ((size_t)kvh * S_LEN + srow) * HD + scol;
    const unsigned short* gv = VTg + ((size_t)kvh * HD + srow) * S_LEN + scol;

#pragma unroll 1
    for (int item = 0; item < 2; ++item) {
        const int qt = (item == 0) ? (15 - g) : g;
        const int q0 = qt * 128;
        const int nt = 2 * qt + 2;
        const int wq = q0 + wave * 16;   // wave's first q row
        const int wqmax = wq + 15;
        const int q = wq + l15;          // THIS lane's q row

        const unsigned short* qp = Q + ((size_t)h * S_LEN + q) * HD + lhi * 8;
        bf16x8 qf0 = *(const bf16x8*)qp;
        bf16x8 qf1 = *(const bf16x8*)(qp + 32);

        f32x4 oacc[4] = {};          // O^T: oacc[db][r] = O[q][db*16+lhi*4+r]
        float mrun = -1e30f, lrun = 0.f;

        GLDS16(gk, &Ks[0][t * 8]);
        GLDS16(gv, &Vs[0][t * 8]);
        __syncthreads();

        int cur = 0;
#pragma unroll 1
        for (int kt = 0; kt < nt; ++kt) {
            const int kv0 = kt * 64;
            if (kt + 1 < nt) {
                GLDS16(gk + (size_t)(kv0 + 64) * HD, &Ks[cur ^ 1][t * 8]);
                GLDS16(gv + (kv0 + 64), &Vs[cur ^ 1][t * 8]);
            }
            if (kv0 <= wqmax) {  // wave-uniform causal skip
                // S^T = K Q^T: sacc[nb][r] = S[q][kv0+nb*16+lhi*4+r]
                f32x4 sacc[4] = {};
#pragma unroll
                for (int nb = 0; nb < 4; nb++) {
                    int krow = nb * 16 + l15;
                    const unsigned short* kb = &Ks[cur][krow * 64];
                    int sw = (krow & 7) * 8;
                    bf16x8 k0v = *(const bf16x8*)&kb[(lhi * 8) ^ sw];
                    bf16x8 k1v = *(const bf16x8*)&kb[(32 + lhi * 8) ^ sw];
                    sacc[nb] = __builtin_amdgcn_mfma_f32_16x16x32_bf16(k0v, qf0, sacc[nb], 0, 0, 0);
                    sacc[nb] = __builtin_amdgcn_mfma_f32_16x16x32_bf16(k1v, qf1, sacc[nb], 0, 0, 0);
                }
                // online softmax: lane owns row q; 16 kv values
                float pv[4][4];
                float rm = -1e30f;
#pragma unroll
                for (int nb = 0; nb < 4; nb++) {
                    int kvb = kv0 + nb * 16 + lhi * 4;
#pragma unroll
                    for (int r = 0; r < 4; r++) {
                        float sv = sacc[nb][r] * cs;
                        sv = (kvb + r <= q) ? sv : -1e30f;
                        pv[nb][r] = sv;
                        rm = fmaxf(rm, sv);
                    }
                }
                rm = fmaxf(rm, __shfl_xor(rm, 16));
                rm = fmaxf(rm, __shfl_xor(rm, 32));
                float mnew = fmaxf(mrun, rm);
                float sc = exp2f(mrun - mnew);
                mrun = mnew;
                lrun *= sc;
#pragma unroll
                for (int db = 0; db < 4; db++) oacc[db] *= sc;
                float rs = 0.f;
#pragma unroll
                for (int nb = 0; nb < 4; nb++)
#pragma unroll
                    for (int r = 0; r < 4; r++) {
                        float e = exp2f(pv[nb][r] - mnew);
                        pv[nb][r] = e;
                        rs += e;
                    }
                rs += __shfl_xor(rs, 16);
                rs += __shfl_xor(rs, 32);
                lrun += rs;
                // pack P^T pairs (static indexing only — no scratch)
                uint32_t pka[4], pkb[4];
#pragma unroll
                for (int nb = 0; nb < 4; nb++) {
                    pka[nb] = cvt_pk_bf16(pv[nb][0], pv[nb][1]);
                    pkb[nb] = cvt_pk_bf16(pv[nb][2], pv[nb][3]);
                }
                const bool selB = ((lhi >> 1) & 1);
                const bool hiR = (lhi & 1);
                const bool sendA = ((lhi ^ (lhi >> 1)) & 1);
#pragma unroll
                for (int ks = 0; ks < 2; ks++) {
                    // own pair = pair(lhi>>1); sent pair (via xor32) = other
                    uint32_t A0 = selB ? pka[2 * ks + 1] : pka[2 * ks];
                    uint32_t A1 = selB ? pkb[2 * ks + 1] : pkb[2 * ks];
                    uint32_t W0 = selB ? pka[2 * ks] : pka[2 * ks + 1];
                    uint32_t W1 = selB ? pkb[2 * ks] : pkb[2 * ks + 1];
                    uint32_t B0 = __shfl_xor((int)W0, 32);
                    uint32_t B1 = __shfl_xor((int)W1, 32);
                    uint32_t S0 = sendA ? A0 : B0, S1 = sendA ? A1 : B1;
                    uint32_t R0 = __shfl_xor((int)S0, 16);
                    uint32_t R1 = __shfl_xor((int)S1, 16);
                    uint32_t F0 = hiR ? R0 : (selB ? B0 : A0);
                    uint32_t F1 = hiR ? R1 : (selB ? B1 : A1);
                    uint32_t F2 = hiR ? (selB ? A0 : B0) : R0;
                    uint32_t F3 = hiR ? (selB ? A1 : B1) : R1;
                    uint4 fu = {F0, F1, F2, F3};
                    bf16x8 pfrag = *(const bf16x8*)&fu;
#pragma unroll
                    for (int db = 0; db < 4; db++) {
                        int vrow = db * 16 + l15;
                        bf16x8 vf = *(const bf16x8*)&Vs[cur][vrow * 64 + ((ks * 32 + lhi * 8) ^ ((vrow & 7) * 8))];
                        oacc[db] = __builtin_amdgcn_mfma_f32_16x16x32_bf16(vf, pfrag, oacc[db], 0, 0, 0);
                    }
                }
            }
            __syncthreads();
            cur ^= 1;
        }
        // epilogue: oacc[db][r] = O[q][db*16+lhi*4+r]; pack pairs, 8B stores
        float rinv = 1.f / lrun;
#pragma unroll
        for (int db = 0; db < 4; db++) {
            uint32_t o0 = cvt_pk_bf16(oacc[db][0] * rinv, oacc[db][1] * rinv);
            uint32_t o1 = cvt_pk_bf16(oacc[db][2] * rinv, oacc[db][3] * rinv);
            uint2 ov = {o0, o1};
            *(uint2*)&O[((size_t)h * S_LEN + q) * HD + db * 16 + lhi * 4] = ov;
        }
    }
}

// ---------------- per-head fw GEMM + SiLU -> h2 bf16 [S][DMODEL] -----------
__global__ __launch_bounds__(256) void fw_silu_kernel(
    const unsigned short* __restrict__ AT, const unsigned short* __restrict__ fwT,
    const float* __restrict__ fb, unsigned short* __restrict__ h2) {
    const int t = threadIdx.x, lane = t & 63, wave = t >> 6;
    const int l15 = lane & 15, lhi = lane >> 4;
    const int r0 = blockIdx.x * 64 + wave * 16;
    const unsigned short* ap = AT + (size_t)(r0 + l15) * HD + lhi * 8;
    bf16x8 a0 = *(const bf16x8*)ap;
    bf16x8 a1 = *(const bf16x8*)(ap + 32);
    f32x4 acc[4] = {};
#pragma unroll
    for (int nb = 0; nb < 4; nb++) {
        const unsigned short* bp = fwT + (size_t)(nb * 16 + l15) * HD + lhi * 8;
        bf16x8 b0 = *(const bf16x8*)bp;
        bf16x8 b1 = *(const bf16x8*)(bp + 32);
        acc[nb] = __builtin_amdgcn_mfma_f32_16x16x32_bf16(a0, b0, acc[nb], 0, 0, 0);
        acc[nb] = __builtin_amdgcn_mfma_f32_16x16x32_bf16(a1, b1, acc[nb], 0, 0, 0);
    }
#pragma unroll
    for (int nb = 0; nb < 4; nb++) {
        int col = nb * 16 + l15;
        float bias = fb[col];
#pragma unroll
        for (int r = 0; r < 4; r++) {
            int row = r0 + lhi * 4 + r;  // h*S + s
            int s = row & (S_LEN - 1), hh = row >> 11;
            float x = acc[nb][r] + bias;
            float sg = 1.f / (1.f + exp2f(-x * 1.44269504f));
            h2[(size_t)s * DMODEL + hh * HD + col] = f2bf(x * sg);
        }
    }
}

extern "C" void kernel_launch(void* const* d_in, const int* in_sizes, int n_in,
                              void* d_out, int out_size, void* d_ws, size_t ws_size,
                              hipStream_t stream) {
    const float* x = (const float*)d_in[0];
    const float* fcos = (const float*)d_in[1];
    const float* fsin = (const float*)d_in[2];
    const float* wq = (const float*)d_in[4];
    const float* wk = (const float*)d_in[5];
    const float* wv = (const float*)d_in[6];
    const float* wo = (const float*)d_in[7];
    const float* fw = (const float*)d_in[8];
    const float* fb = (const float*)d_in[9];
    float* out = (float*)d_out;

    char* ws = (char*)d_ws;
    size_t off = 0;
    auto alloc = [&](size_t bytes) {
        void* p = ws + off;
        off += (bytes + 255) & ~(size_t)255;
        return p;
    };
    unsigned short* wqkvT = (unsigned short*)alloc((size_t)3072 * 2048 * 2);
    unsigned short* woT   = (unsigned short*)alloc((size_t)2048 * 2048 * 2);
    unsigned short* fwT   = (unsigned short*)alloc((size_t)64 * 64 * 2);
    float*          Cqkv  = (float*)alloc((size_t)2048 * 3072 * 4);
    unsigned short* Qb    = (unsigned short*)alloc((size_t)NH * S_LEN * HD * 2);
    unsigned short* Kb    = (unsigned short*)alloc((size_t)NKV * S_LEN * HD * 2);
    unsigned short* VT    = (unsigned short*)alloc((size_t)NKV * HD * S_LEN * 2);
    unsigned short* xb    = (unsigned short*)alloc((size_t)2048 * 2048 * 2);
    // aliases (lifetimes disjoint): attn reuses Cqkv space; h2 reuses xb space
    unsigned short* attn = (unsigned short*)Cqkv;
    unsigned short* h2 = xb;

    dim3 tb(32, 8);
    cast_bf16_kernel<<<2048, 256, 0, stream>>>(x, xb, 2048 * 2048);
    transpose_cast_kernel<<<dim3(64, 64), tb, 0, stream>>>(wq, wqkvT, 2048, 2048);
    transpose_cast_kernel<<<dim3(16, 64), tb, 0, stream>>>(wk, wqkvT + (size_t)2048 * 2048, 2048, 512);
    transpose_cast_kernel<<<dim3(16, 64), tb, 0, stream>>>(wv, wqkvT + (size_t)2560 * 2048, 2048, 512);
    transpose_cast_kernel<<<dim3(64, 64), tb, 0, stream>>>(wo, woT, 2048, 2048);
    transpose_cast_kernel<<<dim3(2, 2), tb, 0, stream>>>(fw, fwT, 64, 64);

    gemm_bt_kernel<<<dim3(16, 24), 256, 0, stream>>>(xb, wqkvT, Cqkv, 2048, 3072, 2048);

    rope_q_kernel<<<8192, 256, 0, stream>>>(Cqkv, fcos, fsin, Qb);
    rope_k_kernel<<<2048, 256, 0, stream>>>(Cqkv, fcos, fsin, Kb);
    v_transpose_kernel<<<dim3(2, 64, 8), tb, 0, stream>>>(Cqkv, VT);

    flash_kernel<<<256, 512, 0, stream>>>(Qb, Kb, VT, attn);

    fw_silu_kernel<<<1024, 256, 0, stream>>>(attn, fwT, fb, h2);

    gemm_bt_kernel<<<dim3(16, 16), 256, 0, stream>>>(h2, woT, out, 2048, 2048, 2048);
}

// Round 5
// 192.562 us; speedup vs baseline: 1.4115x; 1.0716x over previous
//
#include <hip/hip_runtime.h>
#include <stdint.h>

#define S_LEN 2048
#define DMODEL 2048
#define NH 32
#define NKV 8
#define HD 64

typedef __attribute__((ext_vector_type(8))) __bf16 bf16x8;
typedef __attribute__((ext_vector_type(4))) float f32x4;

__device__ __forceinline__ unsigned short f2bf(float f) {
    union { float f; uint32_t u; } v; v.f = f;
    uint32_t u = v.u;
    u += 0x7FFFu + ((u >> 16) & 1u);
    return (unsigned short)(u >> 16);
}

__device__ __forceinline__ uint32_t cvt_pk_bf16(float lo, float hi) {
    uint32_t r;
    asm("v_cvt_pk_bf16_f32 %0, %1, %2" : "=v"(r) : "v"(lo), "v"(hi));
    return r;
}

#define GLDS16(g, l)                                                          \
    __builtin_amdgcn_global_load_lds(                                         \
        (const __attribute__((address_space(1))) unsigned int*)(g),           \
        (__attribute__((address_space(3))) unsigned int*)(l), 16, 0, 0)

// ---------------- elementwise cast fp32 -> bf16 ----------------
__global__ void cast_bf16_kernel(const float* __restrict__ src,
                                 unsigned short* __restrict__ dst, int n) {
    int g = (blockIdx.x * blockDim.x + threadIdx.x) * 8;
    if (g >= n) return;
    float4 a = *(const float4*)&src[g];
    float4 b = *(const float4*)&src[g + 4];
    unsigned short o[8];
    o[0] = f2bf(a.x); o[1] = f2bf(a.y); o[2] = f2bf(a.z); o[3] = f2bf(a.w);
    o[4] = f2bf(b.x); o[5] = f2bf(b.y); o[6] = f2bf(b.z); o[7] = f2bf(b.w);
    *(uint4*)&dst[g] = *(const uint4*)o;
}

// ---------------- tiled transpose + cast: dst[c][r] = bf16(src[r][c]) ------
__global__ void transpose_cast_kernel(const float* __restrict__ src,
                                      unsigned short* __restrict__ dst,
                                      int R, int C) {
    __shared__ float tile[32][33];
    int c0 = blockIdx.x * 32, r0 = blockIdx.y * 32;
    int tx = threadIdx.x, ty = threadIdx.y;
#pragma unroll
    for (int i = 0; i < 32; i += 8)
        tile[ty + i][tx] = src[(size_t)(r0 + ty + i) * C + c0 + tx];
    __syncthreads();
#pragma unroll
    for (int i = 0; i < 32; i += 8)
        dst[(size_t)(c0 + ty + i) * R + r0 + tx] = f2bf(tile[tx][ty + i]);
}

// ------- 2-phase double-buffered bf16 GEMM: C[M][N] = A[M][K] * BT[N][K]^T --
__global__ __launch_bounds__(256) void gemm_bt_kernel(
    const unsigned short* __restrict__ A, const unsigned short* __restrict__ BT,
    float* __restrict__ C, int M, int N, int K) {
    __shared__ unsigned short As[2][128 * 32];
    __shared__ unsigned short Bs[2][128 * 32];
    const int t = threadIdx.x;
    const int lane = t & 63, wave = t >> 6;
    const int wr = wave >> 1, wc = wave & 1;
    const int m0 = blockIdx.x * 128, n0 = blockIdx.y * 128;
    const int l15 = lane & 15, lhi = lane >> 4;
    f32x4 acc[4][4] = {};
    const unsigned short* ga = A + (size_t)(m0 + (t >> 2)) * K + (t & 3) * 8;
    const unsigned short* gb = BT + (size_t)(n0 + (t >> 2)) * K + (t & 3) * 8;

    // prologue: stage K-tile 0 into buffer 0
    GLDS16(ga, &As[0][t * 8]);
    GLDS16(ga + (size_t)64 * K, &As[0][t * 8 + 64 * 32]);
    GLDS16(gb, &Bs[0][t * 8]);
    GLDS16(gb + (size_t)64 * K, &Bs[0][t * 8 + 64 * 32]);
    __syncthreads();

    int cur = 0;
    for (int k0 = 0; k0 < K; k0 += 32) {
        if (k0 + 32 < K) {  // prefetch next K-tile into other buffer
            GLDS16(ga + k0 + 32, &As[cur ^ 1][t * 8]);
            GLDS16(ga + (size_t)64 * K + k0 + 32, &As[cur ^ 1][t * 8 + 64 * 32]);
            GLDS16(gb + k0 + 32, &Bs[cur ^ 1][t * 8]);
            GLDS16(gb + (size_t)64 * K + k0 + 32, &Bs[cur ^ 1][t * 8 + 64 * 32]);
        }
        bf16x8 af[4], bfr[4];
#pragma unroll
        for (int m = 0; m < 4; m++)
            af[m] = *(const bf16x8*)&As[cur][(wr * 64 + m * 16 + l15) * 32 + lhi * 8];
#pragma unroll
        for (int n = 0; n < 4; n++)
            bfr[n] = *(const bf16x8*)&Bs[cur][(wc * 64 + n * 16 + l15) * 32 + lhi * 8];
#pragma unroll
        for (int m = 0; m < 4; m++)
#pragma unroll
            for (int n = 0; n < 4; n++)
                acc[m][n] = __builtin_amdgcn_mfma_f32_16x16x32_bf16(
                    af[m], bfr[n], acc[m][n], 0, 0, 0);
        __syncthreads();
        cur ^= 1;
    }
#pragma unroll
    for (int m = 0; m < 4; m++) {
        int row = m0 + wr * 64 + m * 16 + lhi * 4;
#pragma unroll
        for (int n = 0; n < 4; n++) {
            int col = n0 + wc * 64 + n * 16 + l15;
#pragma unroll
            for (int r = 0; r < 4; r++)
                C[(size_t)(row + r) * N + col] = acc[m][n][r];
        }
    }
}

// ---------------- RoPE for Q: Cqkv fp32 -> Q bf16 [H][S][HD] ---------------
__global__ void rope_q_kernel(const float* __restrict__ Cqkv,
                              const float* __restrict__ cb,
                              const float* __restrict__ sb,
                              unsigned short* __restrict__ Q) {
    int g = blockIdx.x * 256 + threadIdx.x;  // 2048*32*32
    int i = g & 31;
    int h = (g >> 5) & 31;
    int s = g >> 10;
    float2 v = *(const float2*)&Cqkv[(size_t)s * 3072 + h * 64 + 2 * i];
    float cc = cb[s * 32 + i], ss = sb[s * 32 + i];
    ushort2 o;
    o.x = f2bf(v.x * cc - v.y * ss);
    o.y = f2bf(v.x * ss + v.y * cc);
    *(ushort2*)&Q[(size_t)h * (S_LEN * HD) + s * HD + 2 * i] = o;
}

// ---------------- RoPE for K: -> Kb bf16 [NKV][S][HD] ----------------------
__global__ void rope_k_kernel(const float* __restrict__ Cqkv,
                              const float* __restrict__ cb,
                              const float* __restrict__ sb,
                              unsigned short* __restrict__ Kb) {
    int g = blockIdx.x * 256 + threadIdx.x;  // 2048*8*32
    int i = g & 31;
    int kvh = (g >> 5) & 7;
    int s = g >> 8;
    float2 v = *(const float2*)&Cqkv[(size_t)s * 3072 + 2048 + kvh * 64 + 2 * i];
    float cc = cb[s * 32 + i], ss = sb[s * 32 + i];
    ushort2 o;
    o.x = f2bf(v.x * cc - v.y * ss);
    o.y = f2bf(v.x * ss + v.y * cc);
    *(ushort2*)&Kb[(size_t)kvh * (S_LEN * HD) + s * HD + 2 * i] = o;
}

// ---------------- V transpose: Cqkv fp32 -> VT bf16 [NKV][HD][S] -----------
__global__ void v_transpose_kernel(const float* __restrict__ Cqkv,
                                   unsigned short* __restrict__ VT) {
    __shared__ float tile[32][33];
    int kvh = blockIdx.z;
    int d0 = blockIdx.x * 32, s0 = blockIdx.y * 32;
    int tx = threadIdx.x, ty = threadIdx.y;
#pragma unroll
    for (int i = 0; i < 32; i += 8)
        tile[ty + i][tx] =
            Cqkv[(size_t)(s0 + ty + i) * 3072 + 2560 + kvh * 64 + d0 + tx];
    __syncthreads();
#pragma unroll
    for (int i = 0; i < 32; i += 8)
        VT[(size_t)kvh * (HD * S_LEN) + (size_t)(d0 + ty + i) * S_LEN + s0 + tx] =
            f2bf(tile[tx][ty + i]);
}

// ---------------- flash attention v4 -----------------------------------
// 512 blocks, one 128-row q-strip each (2 blocks/CU -> 16 waves/CU).
// Strip map: ss=bid>>5, qt = ss<8 ? ss : 23-ss  (round-robin CU pairs sum
// to 34 tiles). Swapped QK^T, in-register softmax, interior-tile mask skip,
// scale folded into exp2-fma, defer-max (THR=8).
__global__ __launch_bounds__(512) void flash_kernel(
    const unsigned short* __restrict__ Q, const unsigned short* __restrict__ Kg,
    const unsigned short* __restrict__ VTg, unsigned short* __restrict__ O) {
    __shared__ unsigned short Ks[2][4096];
    __shared__ unsigned short Vs[2][4096];
    const int t = threadIdx.x, lane = t & 63, wave = t >> 6;
    const int l15 = lane & 15, lhi = lane >> 4;
    const int bid = blockIdx.x;
    const int h = bid & 31, ss = bid >> 5;
    const int qt = (ss < 8) ? ss : 23 - ss;
    const int kvh = h >> 2;
    const float cs = 0.125f * 1.44269504f;  // 1/sqrt(64) * log2(e)

    const int srow = t >> 3;
    const int scol = ((t & 7) * 8) ^ ((srow & 7) * 8);  // source-side swizzle
    const unsigned short* gk = Kg + ((size_t)kvh * S_LEN + srow) * HD + scol;
    const unsigned short* gv = VTg + ((size_t)kvh * HD + srow) * S_LEN + scol;

    const int q0 = qt * 128;
    const int nt = 2 * qt + 2;
    const int wq = q0 + wave * 16;   // wave's first q row
    const int wqmax = wq + 15;
    const int q = wq + l15;          // THIS lane's q row

    const unsigned short* qp = Q + ((size_t)h * S_LEN + q) * HD + lhi * 8;
    bf16x8 qf0 = *(const bf16x8*)qp;
    bf16x8 qf1 = *(const bf16x8*)(qp + 32);

    f32x4 oacc[4] = {};          // O^T: oacc[db][r] = O[q][db*16+lhi*4+r]
    float mrun = -1e30f, lrun = 0.f;

    GLDS16(gk, &Ks[0][t * 8]);
    GLDS16(gv, &Vs[0][t * 8]);
    __syncthreads();

    int cur = 0;
#pragma unroll 1
    for (int kt = 0; kt < nt; ++kt) {
        const int kv0 = kt * 64;
        if (kt + 1 < nt) {
            GLDS16(gk + (size_t)(kv0 + 64) * HD, &Ks[cur ^ 1][t * 8]);
            GLDS16(gv + (kv0 + 64), &Vs[cur ^ 1][t * 8]);
        }
        if (kv0 <= wqmax) {  // wave-uniform causal skip
            // S^T = K Q^T: sacc[nb][r] = S_raw[q][kv0+nb*16+lhi*4+r]
            f32x4 sacc[4] = {};
#pragma unroll
            for (int nb = 0; nb < 4; nb++) {
                int krow = nb * 16 + l15;
                const unsigned short* kb = &Ks[cur][krow * 64];
                int sw = (krow & 7) * 8;
                bf16x8 k0v = *(const bf16x8*)&kb[(lhi * 8) ^ sw];
                bf16x8 k1v = *(const bf16x8*)&kb[(32 + lhi * 8) ^ sw];
                sacc[nb] = __builtin_amdgcn_mfma_f32_16x16x32_bf16(k0v, qf0, sacc[nb], 0, 0, 0);
                sacc[nb] = __builtin_amdgcn_mfma_f32_16x16x32_bf16(k1v, qf1, sacc[nb], 0, 0, 0);
            }
            // online softmax in raw units; scale folded into exp2-fma
            float pv[4][4];
            float rm = -1e30f;
            if (kv0 + 63 <= wq) {  // interior tile: no masking needed
#pragma unroll
                for (int nb = 0; nb < 4; nb++)
#pragma unroll
                    for (int r = 0; r < 4; r++) {
                        float sv = sacc[nb][r];
                        pv[nb][r] = sv;
                        rm = fmaxf(rm, sv);
                    }
            } else {  // diagonal tile: apply causal mask
#pragma unroll
                for (int nb = 0; nb < 4; nb++) {
                    int kvb = kv0 + nb * 16 + lhi * 4;
#pragma unroll
                    for (int r = 0; r < 4; r++) {
                        float sv = (kvb + r <= q) ? sacc[nb][r] : -1e30f;
                        pv[nb][r] = sv;
                        rm = fmaxf(rm, sv);
                    }
                }
            }
            rm = fmaxf(rm, __shfl_xor(rm, 16));
            rm = fmaxf(rm, __shfl_xor(rm, 32));
            rm *= cs;  // scaled tile max (cs>0: order preserved)
            if (!__all(rm - mrun <= 8.f)) {  // defer-max: rescale only if needed
                float mnew = fmaxf(mrun, rm);
                float sc = exp2f(mrun - mnew);
                mrun = mnew;
                lrun *= sc;
#pragma unroll
                for (int db = 0; db < 4; db++) oacc[db] *= sc;
            }
            float rs = 0.f;
#pragma unroll
            for (int nb = 0; nb < 4; nb++)
#pragma unroll
                for (int r = 0; r < 4; r++) {
                    float e = exp2f(fmaf(pv[nb][r], cs, -mrun));
                    pv[nb][r] = e;
                    rs += e;
                }
            rs += __shfl_xor(rs, 16);
            rs += __shfl_xor(rs, 32);
            lrun += rs;
            // pack P^T pairs (static indexing only — no scratch)
            uint32_t pka[4], pkb[4];
#pragma unroll
            for (int nb = 0; nb < 4; nb++) {
                pka[nb] = cvt_pk_bf16(pv[nb][0], pv[nb][1]);
                pkb[nb] = cvt_pk_bf16(pv[nb][2], pv[nb][3]);
            }
            const bool selB = ((lhi >> 1) & 1);
            const bool hiR = (lhi & 1);
            const bool sendA = ((lhi ^ (lhi >> 1)) & 1);
#pragma unroll
            for (int ks = 0; ks < 2; ks++) {
                uint32_t A0 = selB ? pka[2 * ks + 1] : pka[2 * ks];
                uint32_t A1 = selB ? pkb[2 * ks + 1] : pkb[2 * ks];
                uint32_t W0 = selB ? pka[2 * ks] : pka[2 * ks + 1];
                uint32_t W1 = selB ? pkb[2 * ks] : pkb[2 * ks + 1];
                uint32_t B0 = __shfl_xor((int)W0, 32);
                uint32_t B1 = __shfl_xor((int)W1, 32);
                uint32_t S0 = sendA ? A0 : B0, S1 = sendA ? A1 : B1;
                uint32_t R0 = __shfl_xor((int)S0, 16);
                uint32_t R1 = __shfl_xor((int)S1, 16);
                uint32_t F0 = hiR ? R0 : (selB ? B0 : A0);
                uint32_t F1 = hiR ? R1 : (selB ? B1 : A1);
                uint32_t F2 = hiR ? (selB ? A0 : B0) : R0;
                uint32_t F3 = hiR ? (selB ? A1 : B1) : R1;
                uint4 fu = {F0, F1, F2, F3};
                bf16x8 pfrag = *(const bf16x8*)&fu;
#pragma unroll
                for (int db = 0; db < 4; db++) {
                    int vrow = db * 16 + l15;
                    bf16x8 vf = *(const bf16x8*)&Vs[cur][vrow * 64 + ((ks * 32 + lhi * 8) ^ ((vrow & 7) * 8))];
                    oacc[db] = __builtin_amdgcn_mfma_f32_16x16x32_bf16(vf, pfrag, oacc[db], 0, 0, 0);
                }
            }
        }
        __syncthreads();
        cur ^= 1;
    }
    // epilogue: oacc[db][r] = O[q][db*16+lhi*4+r]; pack pairs, 8B stores
    float rinv = 1.f / lrun;
#pragma unroll
    for (int db = 0; db < 4; db++) {
        uint32_t o0 = cvt_pk_bf16(oacc[db][0] * rinv, oacc[db][1] * rinv);
        uint32_t o1 = cvt_pk_bf16(oacc[db][2] * rinv, oacc[db][3] * rinv);
        uint2 ov = {o0, o1};
        *(uint2*)&O[((size_t)h * S_LEN + q) * HD + db * 16 + lhi * 4] = ov;
    }
}

// ---------------- per-head fw GEMM + SiLU -> h2 bf16 [S][DMODEL] -----------
__global__ __launch_bounds__(256) void fw_silu_kernel(
    const unsigned short* __restrict__ AT, const unsigned short* __restrict__ fwT,
    const float* __restrict__ fb, unsigned short* __restrict__ h2) {
    const int t = threadIdx.x, lane = t & 63, wave = t >> 6;
    const int l15 = lane & 15, lhi = lane >> 4;
    const int r0 = blockIdx.x * 64 + wave * 16;
    const unsigned short* ap = AT + (size_t)(r0 + l15) * HD + lhi * 8;
    bf16x8 a0 = *(const bf16x8*)ap;
    bf16x8 a1 = *(const bf16x8*)(ap + 32);
    f32x4 acc[4] = {};
#pragma unroll
    for (int nb = 0; nb < 4; nb++) {
        const unsigned short* bp = fwT + (size_t)(nb * 16 + l15) * HD + lhi * 8;
        bf16x8 b0 = *(const bf16x8*)bp;
        bf16x8 b1 = *(const bf16x8*)(bp + 32);
        acc[nb] = __builtin_amdgcn_mfma_f32_16x16x32_bf16(a0, b0, acc[nb], 0, 0, 0);
        acc[nb] = __builtin_amdgcn_mfma_f32_16x16x32_bf16(a1, b1, acc[nb], 0, 0, 0);
    }
#pragma unroll
    for (int nb = 0; nb < 4; nb++) {
        int col = nb * 16 + l15;
        float bias = fb[col];
#pragma unroll
        for (int r = 0; r < 4; r++) {
            int row = r0 + lhi * 4 + r;  // h*S + s
            int s = row & (S_LEN - 1), hh = row >> 11;
            float x = acc[nb][r] + bias;
            float sg = 1.f / (1.f + exp2f(-x * 1.44269504f));
            h2[(size_t)s * DMODEL + hh * HD + col] = f2bf(x * sg);
        }
    }
}

extern "C" void kernel_launch(void* const* d_in, const int* in_sizes, int n_in,
                              void* d_out, int out_size, void* d_ws, size_t ws_size,
                              hipStream_t stream) {
    const float* x = (const float*)d_in[0];
    const float* fcos = (const float*)d_in[1];
    const float* fsin = (const float*)d_in[2];
    const float* wq = (const float*)d_in[4];
    const float* wk = (const float*)d_in[5];
    const float* wv = (const float*)d_in[6];
    const float* wo = (const float*)d_in[7];
    const float* fw = (const float*)d_in[8];
    const float* fb = (const float*)d_in[9];
    float* out = (float*)d_out;

    char* ws = (char*)d_ws;
    size_t off = 0;
    auto alloc = [&](size_t bytes) {
        void* p = ws + off;
        off += (bytes + 255) & ~(size_t)255;
        return p;
    };
    unsigned short* wqkvT = (unsigned short*)alloc((size_t)3072 * 2048 * 2);
    unsigned short* woT   = (unsigned short*)alloc((size_t)2048 * 2048 * 2);
    unsigned short* fwT   = (unsigned short*)alloc((size_t)64 * 64 * 2);
    float*          Cqkv  = (float*)alloc((size_t)2048 * 3072 * 4);
    unsigned short* Qb    = (unsigned short*)alloc((size_t)NH * S_LEN * HD * 2);
    unsigned short* Kb    = (unsigned short*)alloc((size_t)NKV * S_LEN * HD * 2);
    unsigned short* VT    = (unsigned short*)alloc((size_t)NKV * HD * S_LEN * 2);
    unsigned short* xb    = (unsigned short*)alloc((size_t)2048 * 2048 * 2);
    // aliases (lifetimes disjoint): attn reuses Cqkv space; h2 reuses xb space
    unsigned short* attn = (unsigned short*)Cqkv;
    unsigned short* h2 = xb;

    dim3 tb(32, 8);
    cast_bf16_kernel<<<2048, 256, 0, stream>>>(x, xb, 2048 * 2048);
    transpose_cast_kernel<<<dim3(64, 64), tb, 0, stream>>>(wq, wqkvT, 2048, 2048);
    transpose_cast_kernel<<<dim3(16, 64), tb, 0, stream>>>(wk, wqkvT + (size_t)2048 * 2048, 2048, 512);
    transpose_cast_kernel<<<dim3(16, 64), tb, 0, stream>>>(wv, wqkvT + (size_t)2560 * 2048, 2048, 512);
    transpose_cast_kernel<<<dim3(64, 64), tb, 0, stream>>>(wo, woT, 2048, 2048);
    transpose_cast_kernel<<<dim3(2, 2), tb, 0, stream>>>(fw, fwT, 64, 64);

    gemm_bt_kernel<<<dim3(16, 24), 256, 0, stream>>>(xb, wqkvT, Cqkv, 2048, 3072, 2048);

    rope_q_kernel<<<8192, 256, 0, stream>>>(Cqkv, fcos, fsin, Qb);
    rope_k_kernel<<<2048, 256, 0, stream>>>(Cqkv, fcos, fsin, Kb);
    v_transpose_kernel<<<dim3(2, 64, 8), tb, 0, stream>>>(Cqkv, VT);

    flash_kernel<<<512, 512, 0, stream>>>(Qb, Kb, VT, attn);

    fw_silu_kernel<<<1024, 256, 0, stream>>>(attn, fwT, fb, h2);

    gemm_bt_kernel<<<dim3(16, 16), 256, 0, stream>>>(h2, woT, out, 2048, 2048, 2048);
}

// Round 6
// 187.894 us; speedup vs baseline: 1.4466x; 1.0248x over previous
//
#include <hip/hip_runtime.h>
#include <stdint.h>

#define S_LEN 2048
#define DMODEL 2048
#define NH 32
#define NKV 8
#define HD 64

typedef __attribute__((ext_vector_type(8))) __bf16 bf16x8;
typedef __attribute__((ext_vector_type(4))) float f32x4;

__device__ __forceinline__ unsigned short f2bf(float f) {
    union { float f; uint32_t u; } v; v.f = f;
    uint32_t u = v.u;
    u += 0x7FFFu + ((u >> 16) & 1u);
    return (unsigned short)(u >> 16);
}

__device__ __forceinline__ uint32_t cvt_pk_bf16(float lo, float hi) {
    uint32_t r;
    asm("v_cvt_pk_bf16_f32 %0, %1, %2" : "=v"(r) : "v"(lo), "v"(hi));
    return r;
}

#define GLDS16(g, l)                                                          \
    __builtin_amdgcn_global_load_lds(                                         \
        (const __attribute__((address_space(1))) unsigned int*)(g),           \
        (__attribute__((address_space(3))) unsigned int*)(l), 16, 0, 0)

// ---------------- elementwise cast fp32 -> bf16 ----------------
__global__ void cast_bf16_kernel(const float* __restrict__ src,
                                 unsigned short* __restrict__ dst, int n) {
    int g = (blockIdx.x * blockDim.x + threadIdx.x) * 8;
    if (g >= n) return;
    float4 a = *(const float4*)&src[g];
    float4 b = *(const float4*)&src[g + 4];
    unsigned short o[8];
    o[0] = f2bf(a.x); o[1] = f2bf(a.y); o[2] = f2bf(a.z); o[3] = f2bf(a.w);
    o[4] = f2bf(b.x); o[5] = f2bf(b.y); o[6] = f2bf(b.z); o[7] = f2bf(b.w);
    *(uint4*)&dst[g] = *(const uint4*)o;
}

// ---------------- tiled transpose + cast: dst[c][r] = bf16(src[r][c]) ------
__global__ void transpose_cast_kernel(const float* __restrict__ src,
                                      unsigned short* __restrict__ dst,
                                      int R, int C) {
    __shared__ float tile[32][33];
    int c0 = blockIdx.x * 32, r0 = blockIdx.y * 32;
    int tx = threadIdx.x, ty = threadIdx.y;
#pragma unroll
    for (int i = 0; i < 32; i += 8)
        tile[ty + i][tx] = src[(size_t)(r0 + ty + i) * C + c0 + tx];
    __syncthreads();
#pragma unroll
    for (int i = 0; i < 32; i += 8)
        dst[(size_t)(c0 + ty + i) * R + r0 + tx] = f2bf(tile[tx][ty + i]);
}

// ------- 2-phase double-buffered bf16 GEMM, optional K-split via blockIdx.z -
// C[M][N] = A[M][koff:koff+Klen] * BT[N][koff:koff+Klen]^T  (Kstride = row
// stride of A/BT). z=0 writes C0, z=1 writes C1 with koff=Klen.
__global__ __launch_bounds__(256) void gemm_bt_kernel(
    const unsigned short* __restrict__ A, const unsigned short* __restrict__ BT,
    float* __restrict__ C0, float* __restrict__ C1, int M, int N,
    int Kstride, int Klen) {
    __shared__ unsigned short As[2][128 * 32];
    __shared__ unsigned short Bs[2][128 * 32];
    const int t = threadIdx.x;
    const int lane = t & 63, wave = t >> 6;
    const int wr = wave >> 1, wc = wave & 1;
    const int m0 = blockIdx.x * 128, n0 = blockIdx.y * 128;
    const int koff = blockIdx.z * Klen;
    float* __restrict__ C = blockIdx.z ? C1 : C0;
    const int l15 = lane & 15, lhi = lane >> 4;
    f32x4 acc[4][4] = {};
    const unsigned short* ga = A + (size_t)(m0 + (t >> 2)) * Kstride + koff + (t & 3) * 8;
    const unsigned short* gb = BT + (size_t)(n0 + (t >> 2)) * Kstride + koff + (t & 3) * 8;

    // prologue: stage K-tile 0 into buffer 0
    GLDS16(ga, &As[0][t * 8]);
    GLDS16(ga + (size_t)64 * Kstride, &As[0][t * 8 + 64 * 32]);
    GLDS16(gb, &Bs[0][t * 8]);
    GLDS16(gb + (size_t)64 * Kstride, &Bs[0][t * 8 + 64 * 32]);
    __syncthreads();

    int cur = 0;
    for (int k0 = 0; k0 < Klen; k0 += 32) {
        if (k0 + 32 < Klen) {  // prefetch next K-tile into other buffer
            GLDS16(ga + k0 + 32, &As[cur ^ 1][t * 8]);
            GLDS16(ga + (size_t)64 * Kstride + k0 + 32, &As[cur ^ 1][t * 8 + 64 * 32]);
            GLDS16(gb + k0 + 32, &Bs[cur ^ 1][t * 8]);
            GLDS16(gb + (size_t)64 * Kstride + k0 + 32, &Bs[cur ^ 1][t * 8 + 64 * 32]);
        }
        bf16x8 af[4], bfr[4];
#pragma unroll
        for (int m = 0; m < 4; m++)
            af[m] = *(const bf16x8*)&As[cur][(wr * 64 + m * 16 + l15) * 32 + lhi * 8];
#pragma unroll
        for (int n = 0; n < 4; n++)
            bfr[n] = *(const bf16x8*)&Bs[cur][(wc * 64 + n * 16 + l15) * 32 + lhi * 8];
#pragma unroll
        for (int m = 0; m < 4; m++)
#pragma unroll
            for (int n = 0; n < 4; n++)
                acc[m][n] = __builtin_amdgcn_mfma_f32_16x16x32_bf16(
                    af[m], bfr[n], acc[m][n], 0, 0, 0);
        __syncthreads();
        cur ^= 1;
    }
#pragma unroll
    for (int m = 0; m < 4; m++) {
        int row = m0 + wr * 64 + m * 16 + lhi * 4;
#pragma unroll
        for (int n = 0; n < 4; n++) {
            int col = n0 + wc * 64 + n * 16 + l15;
#pragma unroll
            for (int r = 0; r < 4; r++)
                C[(size_t)(row + r) * N + col] = acc[m][n][r];
        }
    }
}

// ---------------- out += P1 (fp32, float4) ----------------
__global__ void add_f32_kernel(float* __restrict__ out,
                               const float* __restrict__ p1, int n4) {
    int g = blockIdx.x * blockDim.x + threadIdx.x;
    if (g >= n4) return;
    float4 a = *(const float4*)&out[g * 4];
    float4 b = *(const float4*)&p1[g * 4];
    a.x += b.x; a.y += b.y; a.z += b.z; a.w += b.w;
    *(float4*)&out[g * 4] = a;
}

// -------- RoPE for Q (pre-scaled by 1/sqrt(HD)*log2e): -> Q bf16 [H][S][HD] -
__global__ void rope_q_kernel(const float* __restrict__ Cqkv,
                              const float* __restrict__ cb,
                              const float* __restrict__ sb,
                              unsigned short* __restrict__ Q) {
    const float CS = 0.125f * 1.44269504f;
    int g = blockIdx.x * 256 + threadIdx.x;  // 2048*32*32
    int i = g & 31;
    int h = (g >> 5) & 31;
    int s = g >> 10;
    float2 v = *(const float2*)&Cqkv[(size_t)s * 3072 + h * 64 + 2 * i];
    float cc = cb[s * 32 + i], ss = sb[s * 32 + i];
    ushort2 o;
    o.x = f2bf((v.x * cc - v.y * ss) * CS);
    o.y = f2bf((v.x * ss + v.y * cc) * CS);
    *(ushort2*)&Q[(size_t)h * (S_LEN * HD) + s * HD + 2 * i] = o;
}

// ---------------- RoPE for K: -> Kb bf16 [NKV][S][HD] ----------------------
__global__ void rope_k_kernel(const float* __restrict__ Cqkv,
                              const float* __restrict__ cb,
                              const float* __restrict__ sb,
                              unsigned short* __restrict__ Kb) {
    int g = blockIdx.x * 256 + threadIdx.x;  // 2048*8*32
    int i = g & 31;
    int kvh = (g >> 5) & 7;
    int s = g >> 8;
    float2 v = *(const float2*)&Cqkv[(size_t)s * 3072 + 2048 + kvh * 64 + 2 * i];
    float cc = cb[s * 32 + i], ss = sb[s * 32 + i];
    ushort2 o;
    o.x = f2bf(v.x * cc - v.y * ss);
    o.y = f2bf(v.x * ss + v.y * cc);
    *(ushort2*)&Kb[(size_t)kvh * (S_LEN * HD) + s * HD + 2 * i] = o;
}

// ---------------- V transpose: Cqkv fp32 -> VT bf16 [NKV][HD][S] -----------
__global__ void v_transpose_kernel(const float* __restrict__ Cqkv,
                                   unsigned short* __restrict__ VT) {
    __shared__ float tile[32][33];
    int kvh = blockIdx.z;
    int d0 = blockIdx.x * 32, s0 = blockIdx.y * 32;
    int tx = threadIdx.x, ty = threadIdx.y;
#pragma unroll
    for (int i = 0; i < 32; i += 8)
        tile[ty + i][tx] =
            Cqkv[(size_t)(s0 + ty + i) * 3072 + 2560 + kvh * 64 + d0 + tx];
    __syncthreads();
#pragma unroll
    for (int i = 0; i < 32; i += 8)
        VT[(size_t)kvh * (HD * S_LEN) + (size_t)(d0 + ty + i) * S_LEN + s0 + tx] =
            f2bf(tile[tx][ty + i]);
}

// ---------------- flash attention v5 -----------------------------------
// 1024 blocks x 256 threads (4 waves), one 64-row q-strip per block.
// Snake map u->qt: grp0 0..7 | grp1 15..8 | grp2 16..23 | grp3 31..24 ->
// any 4-round CU assignment sums to 66 tiles (balanced). 4 blocks/CU
// (LDS 32KB each) = 16 waves/CU, 4 independent barrier domains.
// Swapped QK^T (S in exp2 units, Q pre-scaled), in-register softmax with
// local-max defer (cross-lane max reduce only when triggered), per-lane
// lrun partial (reduced in epilogue), in-register P routing to PV.
__global__ __launch_bounds__(256) void flash_kernel(
    const unsigned short* __restrict__ Q, const unsigned short* __restrict__ Kg,
    const unsigned short* __restrict__ VTg, unsigned short* __restrict__ O) {
    __shared__ unsigned short Ks[2][4096];
    __shared__ unsigned short Vs[2][4096];
    const int t = threadIdx.x, lane = t & 63, wave = t >> 6;
    const int l15 = lane & 15, lhi = lane >> 4;
    const int bid = blockIdx.x;
    const int h = bid & 31;
    const int u = bid >> 5;           // 0..31
    const int grp = u >> 3, pos = u & 7;
    const int qt = (grp & 1) ? (grp * 8 + 7 - pos) : (grp * 8 + pos);
    const int kvh = h >> 2;

    const int srow = t >> 3;
    const int scol = ((t & 7) * 8) ^ ((srow & 7) * 8);  // source-side swizzle
    const unsigned short* gk = Kg + ((size_t)kvh * S_LEN + srow) * HD + scol;
    const unsigned short* gv = VTg + ((size_t)kvh * HD + srow) * S_LEN + scol;

    const int q0 = qt * 64;
    const int nt = qt + 1;
    const int wq = q0 + wave * 16;   // wave's first q row
    const int q = wq + l15;          // THIS lane's q row

    const unsigned short* qp = Q + ((size_t)h * S_LEN + q) * HD + lhi * 8;
    bf16x8 qf0 = *(const bf16x8*)qp;
    bf16x8 qf1 = *(const bf16x8*)(qp + 32);

    f32x4 oacc[4] = {};          // O^T: oacc[db][r] = O[q][db*16+lhi*4+r]
    float mrun = -1e30f, lrun = 0.f;

    GLDS16(gk, &Ks[0][t * 8]);
    GLDS16(gk + (size_t)32 * HD, &Ks[0][t * 8 + 2048]);
    GLDS16(gv, &Vs[0][t * 8]);
    GLDS16(gv + (size_t)32 * S_LEN, &Vs[0][t * 8 + 2048]);
    __syncthreads();

    int cur = 0;
#pragma unroll 1
    for (int kt = 0; kt < nt; ++kt) {
        const int kv0 = kt * 64;
        if (kt + 1 < nt) {
            GLDS16(gk + (size_t)(kv0 + 64) * HD, &Ks[cur ^ 1][t * 8]);
            GLDS16(gk + (size_t)(kv0 + 96) * HD, &Ks[cur ^ 1][t * 8 + 2048]);
            GLDS16(gv + (kv0 + 64), &Vs[cur ^ 1][t * 8]);
            GLDS16(gv + (size_t)32 * S_LEN + (kv0 + 64), &Vs[cur ^ 1][t * 8 + 2048]);
        }
        // S^T = K Q^T: sacc[nb][r] = S_log2[q][kv0+nb*16+lhi*4+r]
        f32x4 sacc[4] = {};
#pragma unroll
        for (int nb = 0; nb < 4; nb++) {
            int krow = nb * 16 + l15;
            const unsigned short* kb = &Ks[cur][krow * 64];
            int sw = (krow & 7) * 8;
            bf16x8 k0v = *(const bf16x8*)&kb[(lhi * 8) ^ sw];
            bf16x8 k1v = *(const bf16x8*)&kb[(32 + lhi * 8) ^ sw];
            sacc[nb] = __builtin_amdgcn_mfma_f32_16x16x32_bf16(k0v, qf0, sacc[nb], 0, 0, 0);
            sacc[nb] = __builtin_amdgcn_mfma_f32_16x16x32_bf16(k1v, qf1, sacc[nb], 0, 0, 0);
        }
        // online softmax; lane owns row q (16 kv vals, already exp2-scaled)
        float pv[4][4];
        float lm = -1e30f;
        if (kv0 + 63 <= wq) {  // interior tile: no masking needed
#pragma unroll
            for (int nb = 0; nb < 4; nb++)
#pragma unroll
                for (int r = 0; r < 4; r++) {
                    float sv = sacc[nb][r];
                    pv[nb][r] = sv;
                    lm = fmaxf(lm, sv);
                }
        } else {  // diagonal tile: apply causal mask
#pragma unroll
            for (int nb = 0; nb < 4; nb++) {
                int kvb = kv0 + nb * 16 + lhi * 4;
#pragma unroll
                for (int r = 0; r < 4; r++) {
                    float sv = (kvb + r <= q) ? sacc[nb][r] : -1e30f;
                    pv[nb][r] = sv;
                    lm = fmaxf(lm, sv);
                }
            }
        }
        // local-max defer: cross-lane reduce + rescale only when triggered
        if (!__all(lm - mrun <= 8.f)) {
            float rm = fmaxf(lm, __shfl_xor(lm, 16));
            rm = fmaxf(rm, __shfl_xor(rm, 32));
            float mnew = fmaxf(mrun, rm);
            float sc = exp2f(mrun - mnew);
            mrun = mnew;
            lrun *= sc;
#pragma unroll
            for (int db = 0; db < 4; db++) oacc[db] *= sc;
        }
        float rs = 0.f;
#pragma unroll
        for (int nb = 0; nb < 4; nb++)
#pragma unroll
            for (int r = 0; r < 4; r++) {
                float e = exp2f(pv[nb][r] - mrun);
                pv[nb][r] = e;
                rs += e;
            }
        lrun += rs;  // per-lane partial; reduced in epilogue
        // pack P^T pairs (static indexing only — no scratch)
        uint32_t pka[4], pkb[4];
#pragma unroll
        for (int nb = 0; nb < 4; nb++) {
            pka[nb] = cvt_pk_bf16(pv[nb][0], pv[nb][1]);
            pkb[nb] = cvt_pk_bf16(pv[nb][2], pv[nb][3]);
        }
        const bool selB = ((lhi >> 1) & 1);
        const bool hiR = (lhi & 1);
        const bool sendA = ((lhi ^ (lhi >> 1)) & 1);
#pragma unroll
        for (int ks = 0; ks < 2; ks++) {
            uint32_t A0 = selB ? pka[2 * ks + 1] : pka[2 * ks];
            uint32_t A1 = selB ? pkb[2 * ks + 1] : pkb[2 * ks];
            uint32_t W0 = selB ? pka[2 * ks] : pka[2 * ks + 1];
            uint32_t W1 = selB ? pkb[2 * ks] : pkb[2 * ks + 1];
            uint32_t B0 = __shfl_xor((int)W0, 32);
            uint32_t B1 = __shfl_xor((int)W1, 32);
            uint32_t S0 = sendA ? A0 : B0, S1 = sendA ? A1 : B1;
            uint32_t R0 = __shfl_xor((int)S0, 16);
            uint32_t R1 = __shfl_xor((int)S1, 16);
            uint32_t F0 = hiR ? R0 : (selB ? B0 : A0);
            uint32_t F1 = hiR ? R1 : (selB ? B1 : A1);
            uint32_t F2 = hiR ? (selB ? A0 : B0) : R0;
            uint32_t F3 = hiR ? (selB ? A1 : B1) : R1;
            uint4 fu = {F0, F1, F2, F3};
            bf16x8 pfrag = *(const bf16x8*)&fu;
#pragma unroll
            for (int db = 0; db < 4; db++) {
                int vrow = db * 16 + l15;
                bf16x8 vf = *(const bf16x8*)&Vs[cur][vrow * 64 + ((ks * 32 + lhi * 8) ^ ((vrow & 7) * 8))];
                oacc[db] = __builtin_amdgcn_mfma_f32_16x16x32_bf16(vf, pfrag, oacc[db], 0, 0, 0);
            }
        }
        __syncthreads();
        cur ^= 1;
    }
    // epilogue: reduce lrun across the 4 lane-groups owning row q, normalize
    lrun += __shfl_xor(lrun, 16);
    lrun += __shfl_xor(lrun, 32);
    float rinv = 1.f / lrun;
#pragma unroll
    for (int db = 0; db < 4; db++) {
        uint32_t o0 = cvt_pk_bf16(oacc[db][0] * rinv, oacc[db][1] * rinv);
        uint32_t o1 = cvt_pk_bf16(oacc[db][2] * rinv, oacc[db][3] * rinv);
        uint2 ov = {o0, o1};
        *(uint2*)&O[((size_t)h * S_LEN + q) * HD + db * 16 + lhi * 4] = ov;
    }
}

// ---------------- per-head fw GEMM + SiLU -> h2 bf16 [S][DMODEL] -----------
__global__ __launch_bounds__(256) void fw_silu_kernel(
    const unsigned short* __restrict__ AT, const unsigned short* __restrict__ fwT,
    const float* __restrict__ fb, unsigned short* __restrict__ h2) {
    const int t = threadIdx.x, lane = t & 63, wave = t >> 6;
    const int l15 = lane & 15, lhi = lane >> 4;
    const int r0 = blockIdx.x * 64 + wave * 16;
    const unsigned short* ap = AT + (size_t)(r0 + l15) * HD + lhi * 8;
    bf16x8 a0 = *(const bf16x8*)ap;
    bf16x8 a1 = *(const bf16x8*)(ap + 32);
    f32x4 acc[4] = {};
#pragma unroll
    for (int nb = 0; nb < 4; nb++) {
        const unsigned short* bp = fwT + (size_t)(nb * 16 + l15) * HD + lhi * 8;
        bf16x8 b0 = *(const bf16x8*)bp;
        bf16x8 b1 = *(const bf16x8*)(bp + 32);
        acc[nb] = __builtin_amdgcn_mfma_f32_16x16x32_bf16(a0, b0, acc[nb], 0, 0, 0);
        acc[nb] = __builtin_amdgcn_mfma_f32_16x16x32_bf16(a1, b1, acc[nb], 0, 0, 0);
    }
#pragma unroll
    for (int nb = 0; nb < 4; nb++) {
        int col = nb * 16 + l15;
        float bias = fb[col];
#pragma unroll
        for (int r = 0; r < 4; r++) {
            int row = r0 + lhi * 4 + r;  // h*S + s
            int s = row & (S_LEN - 1), hh = row >> 11;
            float x = acc[nb][r] + bias;
            float sg = 1.f / (1.f + exp2f(-x * 1.44269504f));
            h2[(size_t)s * DMODEL + hh * HD + col] = f2bf(x * sg);
        }
    }
}

extern "C" void kernel_launch(void* const* d_in, const int* in_sizes, int n_in,
                              void* d_out, int out_size, void* d_ws, size_t ws_size,
                              hipStream_t stream) {
    const float* x = (const float*)d_in[0];
    const float* fcos = (const float*)d_in[1];
    const float* fsin = (const float*)d_in[2];
    const float* wq = (const float*)d_in[4];
    const float* wk = (const float*)d_in[5];
    const float* wv = (const float*)d_in[6];
    const float* wo = (const float*)d_in[7];
    const float* fw = (const float*)d_in[8];
    const float* fb = (const float*)d_in[9];
    float* out = (float*)d_out;

    char* ws = (char*)d_ws;
    size_t off = 0;
    auto alloc = [&](size_t bytes) {
        void* p = ws + off;
        off += (bytes + 255) & ~(size_t)255;
        return p;
    };
    unsigned short* wqkvT = (unsigned short*)alloc((size_t)3072 * 2048 * 2);
    unsigned short* woT   = (unsigned short*)alloc((size_t)2048 * 2048 * 2);
    unsigned short* fwT   = (unsigned short*)alloc((size_t)64 * 64 * 2);
    float*          Cqkv  = (float*)alloc((size_t)2048 * 3072 * 4);
    unsigned short* Qb    = (unsigned short*)alloc((size_t)NH * S_LEN * HD * 2);
    unsigned short* Kb    = (unsigned short*)alloc((size_t)NKV * S_LEN * HD * 2);
    unsigned short* VT    = (unsigned short*)alloc((size_t)NKV * HD * S_LEN * 2);
    unsigned short* xb    = (unsigned short*)alloc((size_t)2048 * 2048 * 2);
    // aliases (lifetimes disjoint):
    //   attn (8.39MB) = first part of Cqkv region (Cqkv dead after rope/vtrans)
    //   P1 (16.78MB)  = remainder of Cqkv region (disjoint from attn; exact fit)
    //   h2 reuses xb
    unsigned short* attn = (unsigned short*)Cqkv;
    float* P1 = (float*)((char*)Cqkv + (size_t)NH * S_LEN * HD * 2);
    unsigned short* h2 = xb;

    dim3 tb(32, 8);
    cast_bf16_kernel<<<2048, 256, 0, stream>>>(x, xb, 2048 * 2048);
    transpose_cast_kernel<<<dim3(64, 64), tb, 0, stream>>>(wq, wqkvT, 2048, 2048);
    transpose_cast_kernel<<<dim3(16, 64), tb, 0, stream>>>(wk, wqkvT + (size_t)2048 * 2048, 2048, 512);
    transpose_cast_kernel<<<dim3(16, 64), tb, 0, stream>>>(wv, wqkvT + (size_t)2560 * 2048, 2048, 512);
    transpose_cast_kernel<<<dim3(64, 64), tb, 0, stream>>>(wo, woT, 2048, 2048);
    transpose_cast_kernel<<<dim3(2, 2), tb, 0, stream>>>(fw, fwT, 64, 64);

    gemm_bt_kernel<<<dim3(16, 24, 1), 256, 0, stream>>>(xb, wqkvT, Cqkv, nullptr,
                                                        2048, 3072, 2048, 2048);

    rope_q_kernel<<<8192, 256, 0, stream>>>(Cqkv, fcos, fsin, Qb);
    rope_k_kernel<<<2048, 256, 0, stream>>>(Cqkv, fcos, fsin, Kb);
    v_transpose_kernel<<<dim3(2, 64, 8), tb, 0, stream>>>(Cqkv, VT);

    flash_kernel<<<1024, 256, 0, stream>>>(Qb, Kb, VT, attn);

    fw_silu_kernel<<<1024, 256, 0, stream>>>(attn, fwT, fb, h2);

    // wo GEMM split-K=2: z=0 -> out (K 0..1023), z=1 -> P1 (K 1024..2047)
    gemm_bt_kernel<<<dim3(16, 16, 2), 256, 0, stream>>>(h2, woT, out, P1,
                                                        2048, 2048, 2048, 1024);
    add_f32_kernel<<<4096, 256, 0, stream>>>(out, P1, 1048576);
}